// Round 13
// baseline (461.917 us; speedup 1.0000x reference)
//
#include <hip/hip_runtime.h>
#include <stdint.h>
#include <stddef.h>

#define NN 100000
#define NE 1600000
#define DD 32
#define NCAND 1024
#define HSIZE 65536
#define SORTN 4096
#define NBUK ((NN + 127) / 128)            // 782 buckets of 128 rows
#define EPB 4096                           // edges per block in kA2 (391 blocks)
#define BCAP 2560                          // padded bucket capacity (mean 2048, +11σ)
#define BTB 256                            // kB_emit block size

// capacity for per-stage packed lists (mean + huge margin)
#define CAP1 832000
#define CAP2 432000
#define CAP3 240000

// ---------------- JAX threefry2x32 (20 rounds) ----------------
__host__ __device__ inline void tf2x32(uint32_t k0, uint32_t k1, uint32_t x0, uint32_t x1,
                                       uint32_t& o0, uint32_t& o1) {
  uint32_t ks2 = k0 ^ k1 ^ 0x1BD11BDAu;
  uint32_t v0 = x0 + k0, v1 = x1 + k1;
#define TFR(r) { v0 += v1; v1 = (v1 << (r)) | (v1 >> (32 - (r))); v1 ^= v0; }
  TFR(13) TFR(15) TFR(26) TFR(6)   v0 += k1;  v1 += ks2 + 1u;
  TFR(17) TFR(29) TFR(16) TFR(24)  v0 += ks2; v1 += k0 + 2u;
  TFR(13) TFR(15) TFR(26) TFR(6)   v0 += k0;  v1 += k1 + 3u;
  TFR(17) TFR(29) TFR(16) TFR(24)  v0 += k1;  v1 += ks2 + 4u;
  TFR(13) TFR(15) TFR(26) TFR(6)   v0 += ks2; v1 += k0 + 5u;
#undef TFR
  o0 = v0; o1 = v1;
}

__device__ __forceinline__ uint32_t jax_bits32(uint32_t k0, uint32_t k1, uint32_t i) {
  uint32_t o0, o1;
  tf2x32(k0, k1, 0u, i, o0, o1);
  return o0 ^ o1;
}

__device__ __forceinline__ float bits_to_uniform(uint32_t b) {
  return __fsub_rn(__uint_as_float((b >> 9) | 0x3f800000u), 1.0f);
}

// numpy-pairwise sum of 32 floats
__device__ __forceinline__ float pairwise32(const float* x) {
  float r[8];
#pragma unroll
  for (int j = 0; j < 8; ++j) r[j] = x[j];
#pragma unroll
  for (int b = 8; b < 32; b += 8)
#pragma unroll
    for (int j = 0; j < 8; ++j) r[j] = __fadd_rn(r[j], x[b + j]);
  float a01 = __fadd_rn(r[0], r[1]), a23 = __fadd_rn(r[2], r[3]);
  float a45 = __fadd_rn(r[4], r[5]), a67 = __fadd_rn(r[6], r[7]);
  return __fadd_rn(__fadd_rn(a01, a23), __fadd_rn(a45, a67));
}

// ---------------- preprocessing ----------------

// single edge pass: threefry levels + padded binned scatter.
// rank from first-pass LDS atomic return; per-bucket base from global cursor.
__global__ __launch_bounds__(512) void kA2_bin(
    const int* __restrict__ rows, const int* __restrict__ cols,
    const float* __restrict__ adj,
    uint32_t k00, uint32_t k01, uint32_t k10, uint32_t k11,
    uint32_t k20, uint32_t k21,
    int* __restrict__ bucketCursor, int4* __restrict__ pkBin,
    int* __restrict__ bucketCntS) {
  __shared__ int hist[NBUK];
  __shared__ int base[NBUK];
  __shared__ int h1[NBUK];
  __shared__ int h2[NBUK];
  __shared__ int h3[NBUK];
  __shared__ uint8_t lvs[EPB];
  __shared__ uint16_t rank16[EPB];
  int tid = threadIdx.x;
  for (int i = tid; i < NBUK; i += 512) { hist[i] = 0; h1[i] = 0; h2[i] = 0; h3[i] = 0; }
  __syncthreads();
  int e0 = blockIdx.x * EPB;
  for (int k = 0; k < 8; ++k) {
    int e = e0 + k * 512 + tid;
    int lv = 0;
    if (e < NE) {
      float u0 = bits_to_uniform(jax_bits32(k00, k01, (uint32_t)e));
      float u1 = bits_to_uniform(jax_bits32(k10, k11, (uint32_t)e));
      float u2 = bits_to_uniform(jax_bits32(k20, k21, (uint32_t)e));
      float kp0 = floorf(__fadd_rn(u0, 0.5f));
      float kp1 = floorf(__fadd_rn(u1, 0.25f));
      float kp2 = floorf(__fadd_rn(u2, 0.125f));
      if (kp0 != 0.0f) { lv = 1; if (kp1 != 0.0f) { lv = 2; if (kp2 != 0.0f) lv = 3; } }
      int b = rows[e] >> 7;
      rank16[k * 512 + tid] = (uint16_t)atomicAdd(&hist[b], 1);
      if (lv >= 1) {
        atomicAdd(&h1[b], 1);
        if (lv >= 2) {
          atomicAdd(&h2[b], 1);
          if (lv >= 3) atomicAdd(&h3[b], 1);
        }
      }
    }
    lvs[k * 512 + tid] = (uint8_t)lv;
  }
  __syncthreads();
  for (int i = tid; i < NBUK; i += 512) {
    int h = hist[i];
    base[i] = (h > 0) ? atomicAdd(&bucketCursor[i], h) : 0;
    if (h) atomicAdd(&bucketCntS[i], h);
    if (h1[i]) atomicAdd(&bucketCntS[NBUK + i], h1[i]);
    if (h2[i]) atomicAdd(&bucketCntS[2 * NBUK + i], h2[i]);
    if (h3[i]) atomicAdd(&bucketCntS[3 * NBUK + i], h3[i]);
  }
  __syncthreads();
  for (int k = 0; k < 8; ++k) {
    int e = e0 + k * 512 + tid;
    if (e < NE) {
      int r = rows[e];
      int b = r >> 7;
      int lv = (int)lvs[k * 512 + tid];
      int pos = base[b] + (int)rank16[k * 512 + tid];
      if (pos < BCAP)  // overflow guard (P~0 with +11σ margin)
        pkBin[(size_t)b * BCAP + pos] =
            make_int4(cols[e], __float_as_int(adj[e]), (e << 2) | lv, r);
    }
  }
}

// exclusive scans of the 4 per-bucket count arrays -> bucketBaseS[a][NBUK+1]
__global__ __launch_bounds__(1024) void k_scanBS(const int* __restrict__ bucketCntS,
                                                 int* __restrict__ bucketBaseS) {
  __shared__ int sb[1024];
  int a = blockIdx.x;
  const int* c = bucketCntS + (size_t)a * NBUK;
  int* o = bucketBaseS + (size_t)a * (NBUK + 1);
  int tid = threadIdx.x;
  int v = (tid < NBUK) ? c[tid] : 0;
  sb[tid] = v;
  __syncthreads();
  for (int off = 1; off < 1024; off <<= 1) {
    int x = (tid >= off) ? sb[tid - off] : 0;
    __syncthreads();
    sb[tid] += x;
    __syncthreads();
  }
  if (tid < NBUK) o[tid] = sb[tid] - v;
  if (tid == NBUK - 1) o[NBUK] = sb[tid];
}

// per-bucket (128 rows): count rows, write rpAll, LDS group+sort by eid, emit
__global__ __launch_bounds__(BTB) void kB_emit(
    const int* __restrict__ bucketBaseS, const int4* __restrict__ pkBin,
    int* __restrict__ rpAll,
    int2* __restrict__ pk0, int2* __restrict__ pk1,
    int2* __restrict__ pk2, int2* __restrict__ pk3,
    float* __restrict__ order0, float* __restrict__ order1, float* __restrict__ order2) {
  __shared__ unsigned long long cnt64[128];
  __shared__ unsigned long long sb64[128];
  __shared__ unsigned long long ps64[BTB];
  __shared__ int start0[128];
  __shared__ int cur[128];
  __shared__ uint32_t keyL[BCAP];
  __shared__ uint16_t origL[BCAP];
  int b = blockIdx.x, tid = threadIdx.x;
  int bB0 = bucketBaseS[b];
  int n = bucketBaseS[b + 1] - bB0;
  size_t sRead = (size_t)b * BCAP;
  int r0 = b << 7;
  int nr = NN - r0; if (nr > 128) nr = 128;
  int bB1 = bucketBaseS[(NBUK + 1) + b];
  int bB2 = bucketBaseS[2 * (NBUK + 1) + b];
  int bB3 = bucketBaseS[3 * (NBUK + 1) + b];
  if (tid < 128) { cnt64[tid] = 0ull; cur[tid] = 0; }
  __syncthreads();
  for (int i = tid; i < n; i += BTB) {
    int4 p = pkBin[sRead + i];
    int lr = p.w - r0;
    int lv = p.z & 3;
    unsigned long long add = 1ull;
    if (lv >= 1) add |= 1ull << 16;
    if (lv >= 2) add |= 1ull << 32;
    if (lv >= 3) add |= 1ull << 48;
    atomicAdd(&cnt64[lr], add);
  }
  __syncthreads();
  unsigned long long own = (tid < 128) ? cnt64[tid] : 0ull;
  if (tid < 128) sb64[tid] = own;
  __syncthreads();
  for (int off = 1; off < 128; off <<= 1) {
    unsigned long long v = (tid < 128 && tid >= off) ? sb64[tid - off] : 0ull;
    __syncthreads();
    if (tid < 128) sb64[tid] += v;
    __syncthreads();
  }
  if (tid < 128) {
    unsigned long long ex = sb64[tid] - own;
    start0[tid] = (int)(ex & 0xFFFFull);
    if (tid < nr) {
      rpAll[r0 + tid] = bB0 + (int)(ex & 0xFFFFull);
      rpAll[(NN + 1) + r0 + tid] = bB1 + (int)((ex >> 16) & 0xFFFFull);
      rpAll[2 * (NN + 1) + r0 + tid] = bB2 + (int)((ex >> 32) & 0xFFFFull);
      rpAll[3 * (NN + 1) + r0 + tid] = bB3 + (int)((ex >> 48) & 0xFFFFull);
    }
  }
  if (b == NBUK - 1 && tid == 0) {
    rpAll[NN] = bucketBaseS[NBUK];
    rpAll[(NN + 1) + NN] = bucketBaseS[(NBUK + 1) + NBUK];
    rpAll[2 * (NN + 1) + NN] = bucketBaseS[2 * (NBUK + 1) + NBUK];
    rpAll[3 * (NN + 1) + NN] = bucketBaseS[3 * (NBUK + 1) + NBUK];
  }
  __syncthreads();
  // group into bucket-local LDS slots (rank arbitrary; sorted next)
  for (int i = tid; i < n; i += BTB) {
    int4 p = pkBin[sRead + i];
    int lr = p.w - r0;
    int slot = start0[lr] + atomicAdd(&cur[lr], 1);
    keyL[slot] = (uint32_t)p.z;   // (eid<<2)|lv — unique, eid-ordered
    origL[slot] = (uint16_t)i;
  }
  __syncthreads();
  // per-row insertion sort by key (thread per row)
  if (tid < nr) {
    int d = (int)(cnt64[tid] & 0xFFFFull);
    int st = start0[tid];
    for (int i = 1; i < d; ++i) {
      uint32_t k = keyL[st + i];
      uint16_t o = origL[st + i];
      int j = i - 1;
      while (j >= 0 && keyL[st + j] > k) {
        keyL[st + j + 1] = keyL[st + j];
        origL[st + j + 1] = origL[st + j];
        --j;
      }
      keyL[st + j + 1] = k;
      origL[st + j + 1] = o;
    }
  }
  __syncthreads();
  // orders in sorted (reference) order; adj via L1/L2-hot gathers
  if (tid < nr) {
    int d = (int)(cnt64[tid] & 0xFFFFull);
    int st = start0[tid];
    float o0 = 0.0f, o1v = 0.0f, o2v = 0.0f;
    for (int i = 0; i < d; ++i) {
      uint32_t k = keyL[st + i];
      int lv = (int)(k & 3u);
      float a = __int_as_float(pkBin[sRead + origL[st + i]].y);
      o0 = __fadd_rn(o0, a);
      if (lv >= 1) { o1v = __fadd_rn(o1v, a); if (lv >= 2) o2v = __fadd_rn(o2v, a); }
    }
    order0[r0 + tid] = o0; order1[r0 + tid] = o1v; order2[r0 + tid] = o2v;
  }
  // chunked block scan of stage flags + coalesced emit
  int C = (n + BTB - 1) >> 8;
  int lo = tid * C, hi = lo + C;
  if (lo > n) lo = n;
  if (hi > n) hi = n;
  int c1 = 0, c2 = 0, c3 = 0;
  for (int i = lo; i < hi; ++i) {
    int lv = (int)(keyL[i] & 3u);
    c1 += (lv >= 1); c2 += (lv >= 2); c3 += (lv >= 3);
  }
  unsigned long long mine = (unsigned long long)c1 |
                            ((unsigned long long)c2 << 16) |
                            ((unsigned long long)c3 << 32);
  ps64[tid] = mine;
  __syncthreads();
  for (int off = 1; off < BTB; off <<= 1) {
    unsigned long long v = (tid >= off) ? ps64[tid - off] : 0ull;
    __syncthreads();
    ps64[tid] += v;
    __syncthreads();
  }
  unsigned long long ex = ps64[tid] - mine;
  int o1 = bB1 + (int)(ex & 0xFFFFull);
  int o2 = bB2 + (int)((ex >> 16) & 0xFFFFull);
  int o3 = bB3 + (int)((ex >> 32) & 0xFFFFull);
  for (int i = lo; i < hi; ++i) {
    uint32_t k = keyL[i];
    int lv = (int)(k & 3u);
    int4 p = pkBin[sRead + origL[i]];
    int2 pkv = make_int2(p.x, p.y);
    pk0[bB0 + i] = pkv;  // sequential within bucket
    if (lv >= 1) {
      pk1[o1++] = pkv;
      if (lv >= 2) {
        pk2[o2++] = pkv;
        if (lv >= 3) pk3[o3++] = pkv;
      }
    }
  }
}

// ---------------- SpMM chain (R10-proven shfl-broadcast form) ----------------

// fst_emb = spmm(adj, embeds) - embeds
__global__ void k_emb0(const int* __restrict__ rp, const int2* __restrict__ pk,
                       const float* __restrict__ embeds, float* __restrict__ e0) {
  int tid = blockIdx.x * blockDim.x + threadIdx.x;
  int r = tid >> 5, d = tid & 31;
  if (r >= NN) return;
  int s = rp[r], t = rp[r + 1];
  float acc = 0.0f;
  for (int base = s; base < t; base += 32) {
    int idx = base + d;
    int2 p = (idx < t) ? pk[idx] : make_int2(0, 0);
    int m = t - base; if (m > 32) m = 32;
    for (int j = 0; j < m; ++j) {
      int c = __shfl(p.x, j, 32);
      int ab = __shfl(p.y, j, 32);
      float x = embeds[(size_t)c * DD + d];
      acc = __fadd_rn(acc, __fmul_rn(__int_as_float(ab), x));
    }
  }
  e0[(size_t)r * DD + d] = __fsub_rn(acc, embeds[(size_t)r * DD + d]);
}

// FUSED emb+num step (lane d==0 writes num outputs)
// mode: 1 = sums init, write next; 2 = sums +=, write next; 3 = sums += only
__global__ void k_emb_step(const int* __restrict__ rp, const int2* __restrict__ pk,
                           const float* __restrict__ ord, const float* __restrict__ ecur,
                           float* __restrict__ enext, float* __restrict__ esum,
                           const float* __restrict__ ncur, float* __restrict__ nnext,
                           float* __restrict__ nsum, int mode) {
  int tid = blockIdx.x * blockDim.x + threadIdx.x;
  int r = tid >> 5, d = tid & 31;
  if (r >= NN) return;
  int s = rp[r], t = rp[r + 1];
  float acc = 0.0f, accn = 0.0f;
  for (int base = s; base < t; base += 32) {
    int idx = base + d;
    int2 p = (idx < t) ? pk[idx] : make_int2(0, 0);
    int m = t - base; if (m > 32) m = 32;
    for (int j = 0; j < m; ++j) {
      int c = __shfl(p.x, j, 32);
      int ab = __shfl(p.y, j, 32);
      float av = __int_as_float(ab);
      float x = ecur[(size_t)c * DD + d];
      float xn = ncur[c];  // broadcast load
      acc = __fadd_rn(acc, __fmul_rn(av, x));
      accn = __fadd_rn(accn, __fmul_rn(av, xn));
    }
  }
  float ordv = ord[r];
  size_t idx = (size_t)r * DD + d;
  float ec = ecur[idx];
  float o = __fsub_rn(__fsub_rn(acc, ec), __fmul_rn(ordv, ec));
  if (mode != 3) enext[idx] = o;
  if (mode == 1) esum[idx] = __fadd_rn(ec, o);
  else esum[idx] = __fadd_rn(esum[idx], o);
  if (d == 0) {
    float nc = ncur[r];
    float on = __fsub_rn(__fsub_rn(accn, nc), ordv);
    if (mode != 3) nnext[r] = on;
    if (mode == 1) nsum[r] = __fadd_rn(nc, on);
    else nsum[r] = __fadd_rn(nsum[r], on);
  }
}

__global__ void k_final(const float* __restrict__ embeds, const float* __restrict__ emb_sum,
                        const float* __restrict__ num_sum, uint32_t gk0, uint32_t gk1,
                        float* __restrict__ out_scores, int* __restrict__ hist) {
  int r = blockIdx.x * blockDim.x + threadIdx.x;
  if (r >= NN) return;
  float denom = __fadd_rn(num_sum[r], 1e-8f);
  float sub[DD], em[DD], pr[DD];
  const float4* ps = (const float4*)(emb_sum + (size_t)r * DD);
  const float4* pe = (const float4*)(embeds + (size_t)r * DD);
#pragma unroll
  for (int j = 0; j < 8; ++j) {
    float4 a = ps[j], b = pe[j];
    sub[4 * j + 0] = __fdiv_rn(a.x, denom); sub[4 * j + 1] = __fdiv_rn(a.y, denom);
    sub[4 * j + 2] = __fdiv_rn(a.z, denom); sub[4 * j + 3] = __fdiv_rn(a.w, denom);
    em[4 * j + 0] = b.x; em[4 * j + 1] = b.y; em[4 * j + 2] = b.z; em[4 * j + 3] = b.w;
  }
#pragma unroll
  for (int d = 0; d < DD; ++d) pr[d] = __fmul_rn(sub[d], sub[d]);
  float n1 = fmaxf(__fsqrt_rn(pairwise32(pr)), 1e-12f);
#pragma unroll
  for (int d = 0; d < DD; ++d) pr[d] = __fmul_rn(em[d], em[d]);
  float n2 = fmaxf(__fsqrt_rn(pairwise32(pr)), 1e-12f);
#pragma unroll
  for (int d = 0; d < DD; ++d)
    pr[d] = __fmul_rn(__fdiv_rn(sub[d], n1), __fdiv_rn(em[d], n2));
  float dot = pairwise32(pr);
  float u = bits_to_uniform(jax_bits32(gk0, gk1, (uint32_t)r));
  float l1 = (float)log((double)u);
  float w = -l1;
  float l2 = (float)log((double)w);
  float g = -l2;
  float score = __fadd_rn(dot, g);
  out_scores[r] = score;
  uint32_t kb = __float_as_uint(score);
  kb = (kb & 0x80000000u) ? ~kb : (kb | 0x80000000u);
  atomicAdd(&hist[kb >> 16], 1);
}

__global__ void k_cutoff(const int* __restrict__ hist, int* __restrict__ cutoff) {
  __shared__ int psum[1024];
  int t = threadIdx.x;
  int base = HSIZE - (t + 1) * 64;
  int own = 0;
  for (int i = 0; i < 64; ++i) own += hist[base + i];
  psum[t] = own;
  __syncthreads();
  for (int off = 1; off < 1024; off <<= 1) {
    int v = (t >= off) ? psum[t - off] : 0;
    __syncthreads();
    psum[t] += v;
    __syncthreads();
  }
  int incl = psum[t];
  int prev = incl - own;
  if (incl >= NCAND && prev < NCAND) {
    int c = prev;
    int b = HSIZE - t * 64 - 1;
    while (b >= base) {
      c += hist[b];
      if (c >= NCAND) break;
      --b;
    }
    *cutoff = b;
  }
}

__global__ void k_collect(const float* __restrict__ scores, const int* __restrict__ cutoff,
                          unsigned long long* __restrict__ buf, int* __restrict__ cnt2) {
  int r = blockIdx.x * blockDim.x + threadIdx.x;
  if (r >= NN) return;
  uint32_t kb = __float_as_uint(scores[r]);
  kb = (kb & 0x80000000u) ? ~kb : (kb | 0x80000000u);
  if ((int)(kb >> 16) >= *cutoff) {
    int p = atomicAdd(cnt2, 1);
    if (p < SORTN)
      buf[p] = ((unsigned long long)kb << 32) | (uint32_t)(~(uint32_t)r);
  }
}

__global__ __launch_bounds__(1024) void k_sort(const unsigned long long* __restrict__ buf,
                                               const int* __restrict__ cnt2,
                                               float* __restrict__ out_cand) {
  __shared__ unsigned long long s[SORTN];
  int m = *cnt2;
  if (m > SORTN) m = SORTN;
  for (int i = threadIdx.x; i < SORTN; i += 1024) s[i] = (i < m) ? buf[i] : 0ull;
  __syncthreads();
  for (int k = 2; k <= SORTN; k <<= 1) {
    for (int j = k >> 1; j > 0; j >>= 1) {
      for (int i = threadIdx.x; i < SORTN; i += 1024) {
        int ixj = i ^ j;
        if (ixj > i) {
          unsigned long long a = s[i], b = s[ixj];
          bool desc = ((i & k) == 0);
          if (desc ? (a < b) : (a > b)) { s[i] = b; s[ixj] = a; }
        }
      }
      __syncthreads();
    }
  }
  for (int i = threadIdx.x; i < NCAND; i += 1024) {
    uint32_t idx = ~((uint32_t)(s[i] & 0xffffffffull));
    out_cand[i] = (float)idx;
  }
}

// ---------------- host ----------------
extern "C" void kernel_launch(void* const* d_in, const int* in_sizes, int n_in,
                              void* d_out, int out_size, void* d_ws, size_t ws_size,
                              hipStream_t stream) {
  const int* rows = (const int*)d_in[0];
  const int* cols = rows + NE;
  const float* adj = (const float*)d_in[1];
  const float* embeds = (const float*)d_in[2];
  float* out = (float*)d_out;

  char* p = (char*)d_ws;
  auto alloc = [&](size_t bytes) {
    char* q = p;
    p += (bytes + 255) & ~(size_t)255;
    return q;
  };
  // zero region: bucketCursor(NBUK) | bucketCntS(4*NBUK) | hist(HSIZE) | cnt2(2)
  size_t zero_bytes = (size_t)(5 * NBUK + HSIZE + 8) * 4;
  char* zero_base = (char*)alloc(zero_bytes);
  int* bucketCursor = (int*)zero_base;
  int* bucketCntS = bucketCursor + NBUK;
  int* hist = bucketCntS + 4 * NBUK;
  int* cnt2 = hist + HSIZE;  // [0]=collect count, [1]=cutoff bin

  int* bucketBaseS = (int*)alloc((size_t)4 * (NBUK + 1) * 4);
  int* rpAll = (int*)alloc((size_t)4 * (NN + 1) * 4);
  // padded pkBin (32 MB) dead after kB_emit; embA/embB overlay it
  size_t padBytes = (size_t)NBUK * BCAP * 16;
  char* unionAB = (char*)alloc(padBytes);
  int4* pkBin = (int4*)unionAB;
  float* embA = (float*)unionAB;                           // 12.8 MB
  float* embB = (float*)(unionAB + (size_t)NN * DD * 4);   // 12.8 MB
  int2* pk0 = (int2*)alloc((size_t)NE * 8);
  int2* pk1 = (int2*)alloc((size_t)CAP1 * 8);
  int2* pk2 = (int2*)alloc((size_t)CAP2 * 8);
  int2* pk3 = (int2*)alloc((size_t)CAP3 * 8);
  float* embS = (float*)alloc((size_t)NN * DD * 4);
  float* order0 = (float*)alloc(NN * 4);
  float* order1 = (float*)alloc(NN * 4);
  float* order2 = (float*)alloc(NN * 4);
  float* num1 = (float*)alloc(NN * 4);
  float* num2 = (float*)alloc(NN * 4);
  float* numS = (float*)alloc(NN * 4);
  unsigned long long* buf = (unsigned long long*)alloc(SORTN * 8);

  uint32_t dk[3][2];
  for (int i = 0; i < 3; ++i) tf2x32(0u, 42u, 0u, (uint32_t)i, dk[i][0], dk[i][1]);

  hipMemsetAsync(zero_base, 0, zero_bytes, stream);

  int gE = (NE + EPB - 1) / EPB;  // 391
  kA2_bin<<<gE, 512, 0, stream>>>(rows, cols, adj, dk[0][0], dk[0][1], dk[1][0], dk[1][1],
                                  dk[2][0], dk[2][1], bucketCursor, pkBin, bucketCntS);
  k_scanBS<<<4, 1024, 0, stream>>>(bucketCntS, bucketBaseS);
  kB_emit<<<NBUK, BTB, 0, stream>>>(bucketBaseS, pkBin, rpAll,
                                    pk0, pk1, pk2, pk3, order0, order1, order2);

  const int* rp0 = rpAll;
  const int* rp1 = rpAll + (NN + 1);
  const int* rp2 = rpAll + 2 * (NN + 1);
  const int* rp3 = rpAll + 3 * (NN + 1);

  int gEmb = (NN * 32 + 255) / 256;
  k_emb0<<<gEmb, 256, 0, stream>>>(rp0, pk0, embeds, embA);

  // stage 1: emb cur=embA -> next=embB, num cur=order0 -> num1, sums init
  k_emb_step<<<gEmb, 256, 0, stream>>>(rp1, pk1, order0, embA, embB, embS,
                                       order0, num1, numS, 1);
  // stage 2: emb cur=embB -> next=embA, num cur=num1 -> num2, sums +=
  k_emb_step<<<gEmb, 256, 0, stream>>>(rp2, pk2, order1, embB, embA, embS,
                                       num1, num2, numS, 2);
  // stage 3: sums += only
  k_emb_step<<<gEmb, 256, 0, stream>>>(rp3, pk3, order2, embA, embB, embS,
                                       num2, num1, numS, 3);

  k_final<<<(NN + 255) / 256, 256, 0, stream>>>(embeds, embS, numS, 0u, 7u, out, hist);
  k_cutoff<<<1, 1024, 0, stream>>>(hist, cnt2 + 1);
  k_collect<<<(NN + 255) / 256, 256, 0, stream>>>(out, cnt2 + 1, buf, cnt2);
  k_sort<<<1, 1024, 0, stream>>>(buf, cnt2, out + NN);
}

// Round 14
// 398.706 us; speedup vs baseline: 1.1585x; 1.1585x over previous
//
#include <hip/hip_runtime.h>
#include <stdint.h>
#include <stddef.h>

#define NN 100000
#define NE 1600000
#define DD 32
#define NCAND 1024
#define HSIZE 65536
#define SORTN 4096
#define NBUK ((NN + 255) / 256)            // 391 buckets of 256 rows (R12-proven)
#define EPB 4096                           // edges per block in kA2
#define BCAP 5120                          // padded bucket capacity

// capacity for per-stage packed lists (mean + huge margin)
#define CAP1 832000
#define CAP2 432000
#define CAP3 240000

// ---------------- JAX threefry2x32 (20 rounds) ----------------
__host__ __device__ inline void tf2x32(uint32_t k0, uint32_t k1, uint32_t x0, uint32_t x1,
                                       uint32_t& o0, uint32_t& o1) {
  uint32_t ks2 = k0 ^ k1 ^ 0x1BD11BDAu;
  uint32_t v0 = x0 + k0, v1 = x1 + k1;
#define TFR(r) { v0 += v1; v1 = (v1 << (r)) | (v1 >> (32 - (r))); v1 ^= v0; }
  TFR(13) TFR(15) TFR(26) TFR(6)   v0 += k1;  v1 += ks2 + 1u;
  TFR(17) TFR(29) TFR(16) TFR(24)  v0 += ks2; v1 += k0 + 2u;
  TFR(13) TFR(15) TFR(26) TFR(6)   v0 += k0;  v1 += k1 + 3u;
  TFR(17) TFR(29) TFR(16) TFR(24)  v0 += k1;  v1 += ks2 + 4u;
  TFR(13) TFR(15) TFR(26) TFR(6)   v0 += ks2; v1 += k0 + 5u;
#undef TFR
  o0 = v0; o1 = v1;
}

__device__ __forceinline__ uint32_t jax_bits32(uint32_t k0, uint32_t k1, uint32_t i) {
  uint32_t o0, o1;
  tf2x32(k0, k1, 0u, i, o0, o1);
  return o0 ^ o1;
}

__device__ __forceinline__ float bits_to_uniform(uint32_t b) {
  return __fsub_rn(__uint_as_float((b >> 9) | 0x3f800000u), 1.0f);
}

// numpy-pairwise sum of 32 floats
__device__ __forceinline__ float pairwise32(const float* x) {
  float r[8];
#pragma unroll
  for (int j = 0; j < 8; ++j) r[j] = x[j];
#pragma unroll
  for (int b = 8; b < 32; b += 8)
#pragma unroll
    for (int j = 0; j < 8; ++j) r[j] = __fadd_rn(r[j], x[b + j]);
  float a01 = __fadd_rn(r[0], r[1]), a23 = __fadd_rn(r[2], r[3]);
  float a45 = __fadd_rn(r[4], r[5]), a67 = __fadd_rn(r[6], r[7]);
  return __fadd_rn(__fadd_rn(a01, a23), __fadd_rn(a45, a67));
}

// ---------------- preprocessing (R12-proven) ----------------

__global__ __launch_bounds__(512) void kA2_bin(
    const int* __restrict__ rows, const int* __restrict__ cols,
    const float* __restrict__ adj,
    uint32_t k00, uint32_t k01, uint32_t k10, uint32_t k11,
    uint32_t k20, uint32_t k21,
    int* __restrict__ bucketCursor, int4* __restrict__ pkBin,
    int* __restrict__ bucketCntS) {
  __shared__ int hist[NBUK];
  __shared__ int base[NBUK];
  __shared__ int h1[NBUK];
  __shared__ int h2[NBUK];
  __shared__ int h3[NBUK];
  __shared__ uint8_t lvs[EPB];
  __shared__ uint16_t rank16[EPB];
  int tid = threadIdx.x;
  for (int i = tid; i < NBUK; i += 512) { hist[i] = 0; h1[i] = 0; h2[i] = 0; h3[i] = 0; }
  __syncthreads();
  int e0 = blockIdx.x * EPB;
  for (int k = 0; k < 8; ++k) {
    int e = e0 + k * 512 + tid;
    int lv = 0;
    if (e < NE) {
      float u0 = bits_to_uniform(jax_bits32(k00, k01, (uint32_t)e));
      float u1 = bits_to_uniform(jax_bits32(k10, k11, (uint32_t)e));
      float u2 = bits_to_uniform(jax_bits32(k20, k21, (uint32_t)e));
      float kp0 = floorf(__fadd_rn(u0, 0.5f));
      float kp1 = floorf(__fadd_rn(u1, 0.25f));
      float kp2 = floorf(__fadd_rn(u2, 0.125f));
      if (kp0 != 0.0f) { lv = 1; if (kp1 != 0.0f) { lv = 2; if (kp2 != 0.0f) lv = 3; } }
      int b = rows[e] >> 8;
      rank16[k * 512 + tid] = (uint16_t)atomicAdd(&hist[b], 1);
      if (lv >= 1) {
        atomicAdd(&h1[b], 1);
        if (lv >= 2) {
          atomicAdd(&h2[b], 1);
          if (lv >= 3) atomicAdd(&h3[b], 1);
        }
      }
    }
    lvs[k * 512 + tid] = (uint8_t)lv;
  }
  __syncthreads();
  for (int i = tid; i < NBUK; i += 512) {
    int h = hist[i];
    base[i] = (h > 0) ? atomicAdd(&bucketCursor[i], h) : 0;
    if (h) atomicAdd(&bucketCntS[i], h);
    if (h1[i]) atomicAdd(&bucketCntS[NBUK + i], h1[i]);
    if (h2[i]) atomicAdd(&bucketCntS[2 * NBUK + i], h2[i]);
    if (h3[i]) atomicAdd(&bucketCntS[3 * NBUK + i], h3[i]);
  }
  __syncthreads();
  for (int k = 0; k < 8; ++k) {
    int e = e0 + k * 512 + tid;
    if (e < NE) {
      int r = rows[e];
      int b = r >> 8;
      int lv = (int)lvs[k * 512 + tid];
      int pos = base[b] + (int)rank16[k * 512 + tid];
      if (pos < BCAP)  // overflow guard (P~0)
        pkBin[(size_t)b * BCAP + pos] =
            make_int4(cols[e], __float_as_int(adj[e]), (e << 2) | lv, r);
    }
  }
}

__global__ __launch_bounds__(512) void k_scanBS(const int* __restrict__ bucketCntS,
                                                int* __restrict__ bucketBaseS) {
  __shared__ int sb[512];
  int a = blockIdx.x;
  const int* c = bucketCntS + (size_t)a * NBUK;
  int* o = bucketBaseS + (size_t)a * (NBUK + 1);
  int tid = threadIdx.x;
  int v = (tid < NBUK) ? c[tid] : 0;
  sb[tid] = v;
  __syncthreads();
  for (int off = 1; off < 512; off <<= 1) {
    int x = (tid >= off) ? sb[tid - off] : 0;
    __syncthreads();
    sb[tid] += x;
    __syncthreads();
  }
  if (tid < NBUK) o[tid] = sb[tid] - v;
  if (tid == NBUK - 1) o[NBUK] = sb[tid];
}

__global__ __launch_bounds__(512) void kB_emit(
    const int* __restrict__ bucketBaseS, const int4* __restrict__ pkBin,
    int* __restrict__ rpAll,
    int2* __restrict__ pk0, int2* __restrict__ pk1,
    int2* __restrict__ pk2, int2* __restrict__ pk3,
    float* __restrict__ order0, float* __restrict__ order1, float* __restrict__ order2) {
  __shared__ unsigned long long cnt64[256];
  __shared__ unsigned long long sb64[256];
  __shared__ unsigned long long ps64[512];
  __shared__ int start0[256];
  __shared__ int cur[256];
  __shared__ uint32_t keyL[BCAP];
  __shared__ uint16_t origL[BCAP];
  int b = blockIdx.x, tid = threadIdx.x;
  int bB0 = bucketBaseS[b];
  int n = bucketBaseS[b + 1] - bB0;
  size_t sRead = (size_t)b * BCAP;
  int r0 = b << 8;
  int nr = NN - r0; if (nr > 256) nr = 256;
  int bB1 = bucketBaseS[(NBUK + 1) + b];
  int bB2 = bucketBaseS[2 * (NBUK + 1) + b];
  int bB3 = bucketBaseS[3 * (NBUK + 1) + b];
  if (tid < 256) { cnt64[tid] = 0ull; cur[tid] = 0; }
  __syncthreads();
  for (int i = tid; i < n; i += 512) {
    int4 p = pkBin[sRead + i];
    int lr = p.w - r0;
    int lv = p.z & 3;
    unsigned long long add = 1ull;
    if (lv >= 1) add |= 1ull << 16;
    if (lv >= 2) add |= 1ull << 32;
    if (lv >= 3) add |= 1ull << 48;
    atomicAdd(&cnt64[lr], add);
  }
  __syncthreads();
  unsigned long long own = (tid < 256) ? cnt64[tid] : 0ull;
  if (tid < 256) sb64[tid] = own;
  __syncthreads();
  for (int off = 1; off < 256; off <<= 1) {
    unsigned long long v = (tid < 256 && tid >= off) ? sb64[tid - off] : 0ull;
    __syncthreads();
    if (tid < 256) sb64[tid] += v;
    __syncthreads();
  }
  if (tid < 256) {
    unsigned long long ex = sb64[tid] - own;
    start0[tid] = (int)(ex & 0xFFFFull);
    if (tid < nr) {
      rpAll[r0 + tid] = bB0 + (int)(ex & 0xFFFFull);
      rpAll[(NN + 1) + r0 + tid] = bB1 + (int)((ex >> 16) & 0xFFFFull);
      rpAll[2 * (NN + 1) + r0 + tid] = bB2 + (int)((ex >> 32) & 0xFFFFull);
      rpAll[3 * (NN + 1) + r0 + tid] = bB3 + (int)((ex >> 48) & 0xFFFFull);
    }
  }
  if (b == NBUK - 1 && tid == 0) {
    rpAll[NN] = bucketBaseS[NBUK];
    rpAll[(NN + 1) + NN] = bucketBaseS[(NBUK + 1) + NBUK];
    rpAll[2 * (NN + 1) + NN] = bucketBaseS[2 * (NBUK + 1) + NBUK];
    rpAll[3 * (NN + 1) + NN] = bucketBaseS[3 * (NBUK + 1) + NBUK];
  }
  __syncthreads();
  for (int i = tid; i < n; i += 512) {
    int4 p = pkBin[sRead + i];
    int lr = p.w - r0;
    int slot = start0[lr] + atomicAdd(&cur[lr], 1);
    keyL[slot] = (uint32_t)p.z;
    origL[slot] = (uint16_t)i;
  }
  __syncthreads();
  if (tid < nr) {
    int d = (int)(cnt64[tid] & 0xFFFFull);
    int st = start0[tid];
    for (int i = 1; i < d; ++i) {
      uint32_t k = keyL[st + i];
      uint16_t o = origL[st + i];
      int j = i - 1;
      while (j >= 0 && keyL[st + j] > k) {
        keyL[st + j + 1] = keyL[st + j];
        origL[st + j + 1] = origL[st + j];
        --j;
      }
      keyL[st + j + 1] = k;
      origL[st + j + 1] = o;
    }
  }
  __syncthreads();
  if (tid < nr) {
    int d = (int)(cnt64[tid] & 0xFFFFull);
    int st = start0[tid];
    float o0 = 0.0f, o1v = 0.0f, o2v = 0.0f;
    for (int i = 0; i < d; ++i) {
      uint32_t k = keyL[st + i];
      int lv = (int)(k & 3u);
      float a = __int_as_float(pkBin[sRead + origL[st + i]].y);
      o0 = __fadd_rn(o0, a);
      if (lv >= 1) { o1v = __fadd_rn(o1v, a); if (lv >= 2) o2v = __fadd_rn(o2v, a); }
    }
    order0[r0 + tid] = o0; order1[r0 + tid] = o1v; order2[r0 + tid] = o2v;
  }
  int C = (n + 511) >> 9;
  int lo = tid * C, hi = lo + C;
  if (lo > n) lo = n;
  if (hi > n) hi = n;
  int c1 = 0, c2 = 0, c3 = 0;
  for (int i = lo; i < hi; ++i) {
    int lv = (int)(keyL[i] & 3u);
    c1 += (lv >= 1); c2 += (lv >= 2); c3 += (lv >= 3);
  }
  unsigned long long mine = (unsigned long long)c1 |
                            ((unsigned long long)c2 << 16) |
                            ((unsigned long long)c3 << 32);
  ps64[tid] = mine;
  __syncthreads();
  for (int off = 1; off < 512; off <<= 1) {
    unsigned long long v = (tid >= off) ? ps64[tid - off] : 0ull;
    __syncthreads();
    ps64[tid] += v;
    __syncthreads();
  }
  unsigned long long ex = ps64[tid] - mine;
  int o1 = bB1 + (int)(ex & 0xFFFFull);
  int o2 = bB2 + (int)((ex >> 16) & 0xFFFFull);
  int o3 = bB3 + (int)((ex >> 32) & 0xFFFFull);
  for (int i = lo; i < hi; ++i) {
    uint32_t k = keyL[i];
    int lv = (int)(k & 3u);
    int4 p = pkBin[sRead + origL[i]];
    int2 pkv = make_int2(p.x, p.y);
    pk0[bB0 + i] = pkv;
    if (lv >= 1) {
      pk1[o1++] = pkv;
      if (lv >= 2) {
        pk2[o2++] = pkv;
        if (lv >= 3) pk3[o3++] = pkv;
      }
    }
  }
}

// ---------------- SpMM chain: 8-deep software-pipelined gathers ----------------
// Batch 8 edges: shfl out 8 (c,a) pairs, issue 8 independent gathers, then the
// serial fadd chain. Padding lanes (idx>=t) carry p=(0,0) -> a=+0 products are
// bit-neutral in the chain (acc never becomes -0 after a real add).

// fst_emb = spmm(adj, embeds) - embeds
__global__ void k_emb0(const int* __restrict__ rp, const int2* __restrict__ pk,
                       const float* __restrict__ embeds, float* __restrict__ e0) {
  int tid = blockIdx.x * blockDim.x + threadIdx.x;
  int r = tid >> 5, d = tid & 31;
  if (r >= NN) return;
  int s = rp[r], t = rp[r + 1];
  float acc = 0.0f;
  for (int base = s; base < t; base += 32) {
    int idx = base + d;
    int2 p = (idx < t) ? pk[idx] : make_int2(0, 0);
    int m = t - base; if (m > 32) m = 32;
    for (int j = 0; j < m; j += 8) {
      int cc[8], aa[8];
      float xx[8];
#pragma unroll
      for (int q = 0; q < 8; ++q) {
        cc[q] = __shfl(p.x, j + q, 32);
        aa[q] = __shfl(p.y, j + q, 32);
      }
#pragma unroll
      for (int q = 0; q < 8; ++q) xx[q] = embeds[(size_t)cc[q] * DD + d];
#pragma unroll
      for (int q = 0; q < 8; ++q)
        acc = __fadd_rn(acc, __fmul_rn(__int_as_float(aa[q]), xx[q]));
    }
  }
  e0[(size_t)r * DD + d] = __fsub_rn(acc, embeds[(size_t)r * DD + d]);
}

// FUSED emb+num step (lane d==0 writes num outputs)
// mode: 1 = sums init, write next; 2 = sums +=, write next; 3 = sums += only
__global__ void k_emb_step(const int* __restrict__ rp, const int2* __restrict__ pk,
                           const float* __restrict__ ord, const float* __restrict__ ecur,
                           float* __restrict__ enext, float* __restrict__ esum,
                           const float* __restrict__ ncur, float* __restrict__ nnext,
                           float* __restrict__ nsum, int mode) {
  int tid = blockIdx.x * blockDim.x + threadIdx.x;
  int r = tid >> 5, d = tid & 31;
  if (r >= NN) return;
  int s = rp[r], t = rp[r + 1];
  float acc = 0.0f, accn = 0.0f;
  for (int base = s; base < t; base += 32) {
    int idx = base + d;
    int2 p = (idx < t) ? pk[idx] : make_int2(0, 0);
    int m = t - base; if (m > 32) m = 32;
    for (int j = 0; j < m; j += 8) {
      int cc[8], aa[8];
      float xx[8], nn[8];
#pragma unroll
      for (int q = 0; q < 8; ++q) {
        cc[q] = __shfl(p.x, j + q, 32);
        aa[q] = __shfl(p.y, j + q, 32);
      }
#pragma unroll
      for (int q = 0; q < 8; ++q) {
        xx[q] = ecur[(size_t)cc[q] * DD + d];
        nn[q] = ncur[cc[q]];
      }
#pragma unroll
      for (int q = 0; q < 8; ++q) {
        float av = __int_as_float(aa[q]);
        acc = __fadd_rn(acc, __fmul_rn(av, xx[q]));
        accn = __fadd_rn(accn, __fmul_rn(av, nn[q]));
      }
    }
  }
  float ordv = ord[r];
  size_t idx = (size_t)r * DD + d;
  float ec = ecur[idx];
  float o = __fsub_rn(__fsub_rn(acc, ec), __fmul_rn(ordv, ec));
  if (mode != 3) enext[idx] = o;
  if (mode == 1) esum[idx] = __fadd_rn(ec, o);
  else esum[idx] = __fadd_rn(esum[idx], o);
  if (d == 0) {
    float nc = ncur[r];
    float on = __fsub_rn(__fsub_rn(accn, nc), ordv);
    if (mode != 3) nnext[r] = on;
    if (mode == 1) nsum[r] = __fadd_rn(nc, on);
    else nsum[r] = __fadd_rn(nsum[r], on);
  }
}

__global__ void k_final(const float* __restrict__ embeds, const float* __restrict__ emb_sum,
                        const float* __restrict__ num_sum, uint32_t gk0, uint32_t gk1,
                        float* __restrict__ out_scores, int* __restrict__ hist) {
  int r = blockIdx.x * blockDim.x + threadIdx.x;
  if (r >= NN) return;
  float denom = __fadd_rn(num_sum[r], 1e-8f);
  float sub[DD], em[DD], pr[DD];
  const float4* ps = (const float4*)(emb_sum + (size_t)r * DD);
  const float4* pe = (const float4*)(embeds + (size_t)r * DD);
#pragma unroll
  for (int j = 0; j < 8; ++j) {
    float4 a = ps[j], b = pe[j];
    sub[4 * j + 0] = __fdiv_rn(a.x, denom); sub[4 * j + 1] = __fdiv_rn(a.y, denom);
    sub[4 * j + 2] = __fdiv_rn(a.z, denom); sub[4 * j + 3] = __fdiv_rn(a.w, denom);
    em[4 * j + 0] = b.x; em[4 * j + 1] = b.y; em[4 * j + 2] = b.z; em[4 * j + 3] = b.w;
  }
#pragma unroll
  for (int d = 0; d < DD; ++d) pr[d] = __fmul_rn(sub[d], sub[d]);
  float n1 = fmaxf(__fsqrt_rn(pairwise32(pr)), 1e-12f);
#pragma unroll
  for (int d = 0; d < DD; ++d) pr[d] = __fmul_rn(em[d], em[d]);
  float n2 = fmaxf(__fsqrt_rn(pairwise32(pr)), 1e-12f);
#pragma unroll
  for (int d = 0; d < DD; ++d)
    pr[d] = __fmul_rn(__fdiv_rn(sub[d], n1), __fdiv_rn(em[d], n2));
  float dot = pairwise32(pr);
  float u = bits_to_uniform(jax_bits32(gk0, gk1, (uint32_t)r));
  float l1 = (float)log((double)u);
  float w = -l1;
  float l2 = (float)log((double)w);
  float g = -l2;
  float score = __fadd_rn(dot, g);
  out_scores[r] = score;
  uint32_t kb = __float_as_uint(score);
  kb = (kb & 0x80000000u) ? ~kb : (kb | 0x80000000u);
  atomicAdd(&hist[kb >> 16], 1);
}

__global__ void k_cutoff(const int* __restrict__ hist, int* __restrict__ cutoff) {
  __shared__ int psum[1024];
  int t = threadIdx.x;
  int base = HSIZE - (t + 1) * 64;
  int own = 0;
  for (int i = 0; i < 64; ++i) own += hist[base + i];
  psum[t] = own;
  __syncthreads();
  for (int off = 1; off < 1024; off <<= 1) {
    int v = (t >= off) ? psum[t - off] : 0;
    __syncthreads();
    psum[t] += v;
    __syncthreads();
  }
  int incl = psum[t];
  int prev = incl - own;
  if (incl >= NCAND && prev < NCAND) {
    int c = prev;
    int b = HSIZE - t * 64 - 1;
    while (b >= base) {
      c += hist[b];
      if (c >= NCAND) break;
      --b;
    }
    *cutoff = b;
  }
}

__global__ void k_collect(const float* __restrict__ scores, const int* __restrict__ cutoff,
                          unsigned long long* __restrict__ buf, int* __restrict__ cnt2) {
  int r = blockIdx.x * blockDim.x + threadIdx.x;
  if (r >= NN) return;
  uint32_t kb = __float_as_uint(scores[r]);
  kb = (kb & 0x80000000u) ? ~kb : (kb | 0x80000000u);
  if ((int)(kb >> 16) >= *cutoff) {
    int p = atomicAdd(cnt2, 1);
    if (p < SORTN)
      buf[p] = ((unsigned long long)kb << 32) | (uint32_t)(~(uint32_t)r);
  }
}

__global__ __launch_bounds__(1024) void k_sort(const unsigned long long* __restrict__ buf,
                                               const int* __restrict__ cnt2,
                                               float* __restrict__ out_cand) {
  __shared__ unsigned long long s[SORTN];
  int m = *cnt2;
  if (m > SORTN) m = SORTN;
  for (int i = threadIdx.x; i < SORTN; i += 1024) s[i] = (i < m) ? buf[i] : 0ull;
  __syncthreads();
  for (int k = 2; k <= SORTN; k <<= 1) {
    for (int j = k >> 1; j > 0; j >>= 1) {
      for (int i = threadIdx.x; i < SORTN; i += 1024) {
        int ixj = i ^ j;
        if (ixj > i) {
          unsigned long long a = s[i], b = s[ixj];
          bool desc = ((i & k) == 0);
          if (desc ? (a < b) : (a > b)) { s[i] = b; s[ixj] = a; }
        }
      }
      __syncthreads();
    }
  }
  for (int i = threadIdx.x; i < NCAND; i += 1024) {
    uint32_t idx = ~((uint32_t)(s[i] & 0xffffffffull));
    out_cand[i] = (float)idx;
  }
}

// ---------------- host ----------------
extern "C" void kernel_launch(void* const* d_in, const int* in_sizes, int n_in,
                              void* d_out, int out_size, void* d_ws, size_t ws_size,
                              hipStream_t stream) {
  const int* rows = (const int*)d_in[0];
  const int* cols = rows + NE;
  const float* adj = (const float*)d_in[1];
  const float* embeds = (const float*)d_in[2];
  float* out = (float*)d_out;

  char* p = (char*)d_ws;
  auto alloc = [&](size_t bytes) {
    char* q = p;
    p += (bytes + 255) & ~(size_t)255;
    return q;
  };
  size_t zero_bytes = (size_t)(5 * NBUK + HSIZE + 8) * 4;
  char* zero_base = (char*)alloc(zero_bytes);
  int* bucketCursor = (int*)zero_base;
  int* bucketCntS = bucketCursor + NBUK;
  int* hist = bucketCntS + 4 * NBUK;
  int* cnt2 = hist + HSIZE;  // [0]=collect count, [1]=cutoff bin

  int* bucketBaseS = (int*)alloc((size_t)4 * (NBUK + 1) * 4);
  int* rpAll = (int*)alloc((size_t)4 * (NN + 1) * 4);
  // padded pkBin (32 MB) dead after kB_emit; embA/embB overlay it
  size_t padBytes = (size_t)NBUK * BCAP * 16;
  char* unionAB = (char*)alloc(padBytes);
  int4* pkBin = (int4*)unionAB;
  float* embA = (float*)unionAB;                           // 12.8 MB
  float* embB = (float*)(unionAB + (size_t)NN * DD * 4);   // 12.8 MB
  int2* pk0 = (int2*)alloc((size_t)NE * 8);
  int2* pk1 = (int2*)alloc((size_t)CAP1 * 8);
  int2* pk2 = (int2*)alloc((size_t)CAP2 * 8);
  int2* pk3 = (int2*)alloc((size_t)CAP3 * 8);
  float* embS = (float*)alloc((size_t)NN * DD * 4);
  float* order0 = (float*)alloc(NN * 4);
  float* order1 = (float*)alloc(NN * 4);
  float* order2 = (float*)alloc(NN * 4);
  float* num1 = (float*)alloc(NN * 4);
  float* num2 = (float*)alloc(NN * 4);
  float* numS = (float*)alloc(NN * 4);
  unsigned long long* buf = (unsigned long long*)alloc(SORTN * 8);

  uint32_t dk[3][2];
  for (int i = 0; i < 3; ++i) tf2x32(0u, 42u, 0u, (uint32_t)i, dk[i][0], dk[i][1]);

  hipMemsetAsync(zero_base, 0, zero_bytes, stream);

  int gE = (NE + EPB - 1) / EPB;  // 391
  kA2_bin<<<gE, 512, 0, stream>>>(rows, cols, adj, dk[0][0], dk[0][1], dk[1][0], dk[1][1],
                                  dk[2][0], dk[2][1], bucketCursor, pkBin, bucketCntS);
  k_scanBS<<<4, 512, 0, stream>>>(bucketCntS, bucketBaseS);
  kB_emit<<<NBUK, 512, 0, stream>>>(bucketBaseS, pkBin, rpAll,
                                    pk0, pk1, pk2, pk3, order0, order1, order2);

  const int* rp0 = rpAll;
  const int* rp1 = rpAll + (NN + 1);
  const int* rp2 = rpAll + 2 * (NN + 1);
  const int* rp3 = rpAll + 3 * (NN + 1);

  int gEmb = (NN * 32 + 255) / 256;
  k_emb0<<<gEmb, 256, 0, stream>>>(rp0, pk0, embeds, embA);

  // stage 1: emb cur=embA -> next=embB, num cur=order0 -> num1, sums init
  k_emb_step<<<gEmb, 256, 0, stream>>>(rp1, pk1, order0, embA, embB, embS,
                                       order0, num1, numS, 1);
  // stage 2: emb cur=embB -> next=embA, num cur=num1 -> num2, sums +=
  k_emb_step<<<gEmb, 256, 0, stream>>>(rp2, pk2, order1, embB, embA, embS,
                                       num1, num2, numS, 2);
  // stage 3: sums += only
  k_emb_step<<<gEmb, 256, 0, stream>>>(rp3, pk3, order2, embA, embB, embS,
                                       num2, num1, numS, 3);

  k_final<<<(NN + 255) / 256, 256, 0, stream>>>(embeds, embS, numS, 0u, 7u, out, hist);
  k_cutoff<<<1, 1024, 0, stream>>>(hist, cnt2 + 1);
  k_collect<<<(NN + 255) / 256, 256, 0, stream>>>(out, cnt2 + 1, buf, cnt2);
  k_sort<<<1, 1024, 0, stream>>>(buf, cnt2, out + NN);
}

// Round 15
// 391.963 us; speedup vs baseline: 1.1785x; 1.0172x over previous
//
#include <hip/hip_runtime.h>
#include <stdint.h>
#include <stddef.h>

#define NN 100000
#define NE 1600000
#define DD 32
#define NCAND 1024
#define HSIZE 65536
#define SORTN 4096
#define NBUK ((NN + 255) / 256)            // 391 buckets of 256 rows
#define EPB 4096                           // edges per block in kA2
#define BCAP 5120                          // padded bucket capacity

// capacity for per-stage packed lists (mean + huge margin)
#define CAP1 832000
#define CAP2 432000
#define CAP3 240000

// ---------------- JAX threefry2x32 (20 rounds) ----------------
__host__ __device__ inline void tf2x32(uint32_t k0, uint32_t k1, uint32_t x0, uint32_t x1,
                                       uint32_t& o0, uint32_t& o1) {
  uint32_t ks2 = k0 ^ k1 ^ 0x1BD11BDAu;
  uint32_t v0 = x0 + k0, v1 = x1 + k1;
#define TFR(r) { v0 += v1; v1 = (v1 << (r)) | (v1 >> (32 - (r))); v1 ^= v0; }
  TFR(13) TFR(15) TFR(26) TFR(6)   v0 += k1;  v1 += ks2 + 1u;
  TFR(17) TFR(29) TFR(16) TFR(24)  v0 += ks2; v1 += k0 + 2u;
  TFR(13) TFR(15) TFR(26) TFR(6)   v0 += k0;  v1 += k1 + 3u;
  TFR(17) TFR(29) TFR(16) TFR(24)  v0 += k1;  v1 += ks2 + 4u;
  TFR(13) TFR(15) TFR(26) TFR(6)   v0 += ks2; v1 += k0 + 5u;
#undef TFR
  o0 = v0; o1 = v1;
}

__device__ __forceinline__ uint32_t jax_bits32(uint32_t k0, uint32_t k1, uint32_t i) {
  uint32_t o0, o1;
  tf2x32(k0, k1, 0u, i, o0, o1);
  return o0 ^ o1;
}

__device__ __forceinline__ float bits_to_uniform(uint32_t b) {
  return __fsub_rn(__uint_as_float((b >> 9) | 0x3f800000u), 1.0f);
}

// numpy-pairwise sum of 32 floats
__device__ __forceinline__ float pairwise32(const float* x) {
  float r[8];
#pragma unroll
  for (int j = 0; j < 8; ++j) r[j] = x[j];
#pragma unroll
  for (int b = 8; b < 32; b += 8)
#pragma unroll
    for (int j = 0; j < 8; ++j) r[j] = __fadd_rn(r[j], x[b + j]);
  float a01 = __fadd_rn(r[0], r[1]), a23 = __fadd_rn(r[2], r[3]);
  float a45 = __fadd_rn(r[4], r[5]), a67 = __fadd_rn(r[6], r[7]);
  return __fadd_rn(__fadd_rn(a01, a23), __fadd_rn(a45, a67));
}

// ---------------- preprocessing ----------------

__global__ __launch_bounds__(512) void kA2_bin(
    const int* __restrict__ rows, const int* __restrict__ cols,
    const float* __restrict__ adj,
    uint32_t k00, uint32_t k01, uint32_t k10, uint32_t k11,
    uint32_t k20, uint32_t k21,
    int* __restrict__ bucketCursor, int4* __restrict__ pkBin,
    int* __restrict__ bucketCntS) {
  __shared__ int hist[NBUK];
  __shared__ int base[NBUK];
  __shared__ int h1[NBUK];
  __shared__ int h2[NBUK];
  __shared__ int h3[NBUK];
  __shared__ uint8_t lvs[EPB];
  __shared__ uint16_t rank16[EPB];
  int tid = threadIdx.x;
  for (int i = tid; i < NBUK; i += 512) { hist[i] = 0; h1[i] = 0; h2[i] = 0; h3[i] = 0; }
  __syncthreads();
  int e0 = blockIdx.x * EPB;
  for (int k = 0; k < 8; ++k) {
    int e = e0 + k * 512 + tid;
    int lv = 0;
    if (e < NE) {
      float u0 = bits_to_uniform(jax_bits32(k00, k01, (uint32_t)e));
      float u1 = bits_to_uniform(jax_bits32(k10, k11, (uint32_t)e));
      float u2 = bits_to_uniform(jax_bits32(k20, k21, (uint32_t)e));
      float kp0 = floorf(__fadd_rn(u0, 0.5f));
      float kp1 = floorf(__fadd_rn(u1, 0.25f));
      float kp2 = floorf(__fadd_rn(u2, 0.125f));
      if (kp0 != 0.0f) { lv = 1; if (kp1 != 0.0f) { lv = 2; if (kp2 != 0.0f) lv = 3; } }
      int b = rows[e] >> 8;
      rank16[k * 512 + tid] = (uint16_t)atomicAdd(&hist[b], 1);
      if (lv >= 1) {
        atomicAdd(&h1[b], 1);
        if (lv >= 2) {
          atomicAdd(&h2[b], 1);
          if (lv >= 3) atomicAdd(&h3[b], 1);
        }
      }
    }
    lvs[k * 512 + tid] = (uint8_t)lv;
  }
  __syncthreads();
  for (int i = tid; i < NBUK; i += 512) {
    int h = hist[i];
    base[i] = (h > 0) ? atomicAdd(&bucketCursor[i], h) : 0;
    if (h) atomicAdd(&bucketCntS[i], h);
    if (h1[i]) atomicAdd(&bucketCntS[NBUK + i], h1[i]);
    if (h2[i]) atomicAdd(&bucketCntS[2 * NBUK + i], h2[i]);
    if (h3[i]) atomicAdd(&bucketCntS[3 * NBUK + i], h3[i]);
  }
  __syncthreads();
  for (int k = 0; k < 8; ++k) {
    int e = e0 + k * 512 + tid;
    if (e < NE) {
      int r = rows[e];
      int b = r >> 8;
      int lv = (int)lvs[k * 512 + tid];
      int pos = base[b] + (int)rank16[k * 512 + tid];
      if (pos < BCAP)  // overflow guard (P~0)
        pkBin[(size_t)b * BCAP + pos] =
            make_int4(cols[e], __float_as_int(adj[e]), (e << 2) | lv, r);
    }
  }
}

__global__ __launch_bounds__(512) void k_scanBS(const int* __restrict__ bucketCntS,
                                                int* __restrict__ bucketBaseS) {
  __shared__ int sb[512];
  int a = blockIdx.x;
  const int* c = bucketCntS + (size_t)a * NBUK;
  int* o = bucketBaseS + (size_t)a * (NBUK + 1);
  int tid = threadIdx.x;
  int v = (tid < NBUK) ? c[tid] : 0;
  sb[tid] = v;
  __syncthreads();
  for (int off = 1; off < 512; off <<= 1) {
    int x = (tid >= off) ? sb[tid - off] : 0;
    __syncthreads();
    sb[tid] += x;
    __syncthreads();
  }
  if (tid < NBUK) o[tid] = sb[tid] - v;
  if (tid == NBUK - 1) o[NBUK] = sb[tid];
}

// per-bucket: ONE global pass stashes key+payload in LDS; group, sort,
// order sums, and coalesced emit all run from LDS (no random L2 gathers).
__global__ __launch_bounds__(512) void kB_emit(
    const int* __restrict__ bucketBaseS, const int4* __restrict__ pkBin,
    int* __restrict__ rpAll,
    int2* __restrict__ pk0, int2* __restrict__ pk1,
    int2* __restrict__ pk2, int2* __restrict__ pk3,
    float* __restrict__ order0, float* __restrict__ order1, float* __restrict__ order2) {
  __shared__ unsigned long long cnt64[256];
  __shared__ unsigned long long sb64[256];
  __shared__ unsigned long long ps64[512];
  __shared__ int start0[256];
  __shared__ int cur[256];
  __shared__ uint32_t keyF[BCAP];   // (lr<<23)|(eid<<2)|lv  (31 bits)
  __shared__ int2 payL[BCAP];       // (col, adj_bits)
  __shared__ uint16_t origG[BCAP];  // grouped slot -> original index
  int b = blockIdx.x, tid = threadIdx.x;
  int bB0 = bucketBaseS[b];
  int n = bucketBaseS[b + 1] - bB0;
  if (n > BCAP) n = BCAP;  // LDS-safety clamp (P~0)
  size_t sRead = (size_t)b * BCAP;
  int r0 = b << 8;
  int nr = NN - r0; if (nr > 256) nr = 256;
  int bB1 = bucketBaseS[(NBUK + 1) + b];
  int bB2 = bucketBaseS[2 * (NBUK + 1) + b];
  int bB3 = bucketBaseS[3 * (NBUK + 1) + b];
  if (tid < 256) { cnt64[tid] = 0ull; cur[tid] = 0; }
  __syncthreads();
  // single global pass: load, stash, count
  for (int i = tid; i < n; i += 512) {
    int4 p = pkBin[sRead + i];
    int lr = p.w - r0;
    int lv = p.z & 3;
    keyF[i] = ((uint32_t)lr << 23) | (uint32_t)p.z;
    payL[i] = make_int2(p.x, p.y);
    unsigned long long add = 1ull;
    if (lv >= 1) add |= 1ull << 16;
    if (lv >= 2) add |= 1ull << 32;
    if (lv >= 3) add |= 1ull << 48;
    atomicAdd(&cnt64[lr], add);
  }
  __syncthreads();
  unsigned long long own = (tid < 256) ? cnt64[tid] : 0ull;
  if (tid < 256) sb64[tid] = own;
  __syncthreads();
  for (int off = 1; off < 256; off <<= 1) {
    unsigned long long v = (tid < 256 && tid >= off) ? sb64[tid - off] : 0ull;
    __syncthreads();
    if (tid < 256) sb64[tid] += v;
    __syncthreads();
  }
  if (tid < 256) {
    unsigned long long ex = sb64[tid] - own;
    start0[tid] = (int)(ex & 0xFFFFull);
    if (tid < nr) {
      rpAll[r0 + tid] = bB0 + (int)(ex & 0xFFFFull);
      rpAll[(NN + 1) + r0 + tid] = bB1 + (int)((ex >> 16) & 0xFFFFull);
      rpAll[2 * (NN + 1) + r0 + tid] = bB2 + (int)((ex >> 32) & 0xFFFFull);
      rpAll[3 * (NN + 1) + r0 + tid] = bB3 + (int)((ex >> 48) & 0xFFFFull);
    }
  }
  if (b == NBUK - 1 && tid == 0) {
    rpAll[NN] = bucketBaseS[NBUK];
    rpAll[(NN + 1) + NN] = bucketBaseS[(NBUK + 1) + NBUK];
    rpAll[2 * (NN + 1) + NN] = bucketBaseS[2 * (NBUK + 1) + NBUK];
    rpAll[3 * (NN + 1) + NN] = bucketBaseS[3 * (NBUK + 1) + NBUK];
  }
  __syncthreads();
  // group (LDS->LDS)
  for (int i = tid; i < n; i += 512) {
    int lr = (int)(keyF[i] >> 23);
    int slot = start0[lr] + atomicAdd(&cur[lr], 1);
    origG[slot] = (uint16_t)i;
  }
  __syncthreads();
  // per-row insertion sort of origG by keyF[origG[.]]
  if (tid < nr) {
    int d = (int)(cnt64[tid] & 0xFFFFull);
    int st = start0[tid];
    for (int i = 1; i < d; ++i) {
      uint16_t oi = origG[st + i];
      uint32_t ki = keyF[oi];
      int j = i - 1;
      while (j >= 0) {
        uint16_t oj = origG[st + j];
        if (keyF[oj] <= ki) break;
        origG[st + j + 1] = oj;
        --j;
      }
      origG[st + j + 1] = oi;
    }
  }
  __syncthreads();
  // orders in sorted (reference) order — all LDS
  if (tid < nr) {
    int d = (int)(cnt64[tid] & 0xFFFFull);
    int st = start0[tid];
    float o0 = 0.0f, o1v = 0.0f, o2v = 0.0f;
    for (int i = 0; i < d; ++i) {
      uint16_t o = origG[st + i];
      int lv = (int)(keyF[o] & 3u);
      float a = __int_as_float(payL[o].y);
      o0 = __fadd_rn(o0, a);
      if (lv >= 1) { o1v = __fadd_rn(o1v, a); if (lv >= 2) o2v = __fadd_rn(o2v, a); }
    }
    order0[r0 + tid] = o0; order1[r0 + tid] = o1v; order2[r0 + tid] = o2v;
  }
  // chunked block scan of stage flags + coalesced emit — all LDS
  int C = (n + 511) >> 9;
  int lo = tid * C, hi = lo + C;
  if (lo > n) lo = n;
  if (hi > n) hi = n;
  int c1 = 0, c2 = 0, c3 = 0;
  for (int i = lo; i < hi; ++i) {
    int lv = (int)(keyF[origG[i]] & 3u);
    c1 += (lv >= 1); c2 += (lv >= 2); c3 += (lv >= 3);
  }
  unsigned long long mine = (unsigned long long)c1 |
                            ((unsigned long long)c2 << 16) |
                            ((unsigned long long)c3 << 32);
  ps64[tid] = mine;
  __syncthreads();
  for (int off = 1; off < 512; off <<= 1) {
    unsigned long long v = (tid >= off) ? ps64[tid - off] : 0ull;
    __syncthreads();
    ps64[tid] += v;
    __syncthreads();
  }
  unsigned long long ex = ps64[tid] - mine;
  int o1 = bB1 + (int)(ex & 0xFFFFull);
  int o2 = bB2 + (int)((ex >> 16) & 0xFFFFull);
  int o3 = bB3 + (int)((ex >> 32) & 0xFFFFull);
  for (int i = lo; i < hi; ++i) {
    uint16_t o = origG[i];
    int lv = (int)(keyF[o] & 3u);
    int2 pkv = payL[o];
    pk0[bB0 + i] = pkv;  // sequential within bucket
    if (lv >= 1) {
      pk1[o1++] = pkv;
      if (lv >= 2) {
        pk2[o2++] = pkv;
        if (lv >= 3) pk3[o3++] = pkv;
      }
    }
  }
}

// ---------------- SpMM chain: 8-deep software-pipelined gathers ----------------

// fst_emb = spmm(adj, embeds) - embeds
__global__ void k_emb0(const int* __restrict__ rp, const int2* __restrict__ pk,
                       const float* __restrict__ embeds, float* __restrict__ e0) {
  int tid = blockIdx.x * blockDim.x + threadIdx.x;
  int r = tid >> 5, d = tid & 31;
  if (r >= NN) return;
  int s = rp[r], t = rp[r + 1];
  float acc = 0.0f;
  for (int base = s; base < t; base += 32) {
    int idx = base + d;
    int2 p = (idx < t) ? pk[idx] : make_int2(0, 0);
    int m = t - base; if (m > 32) m = 32;
    for (int j = 0; j < m; j += 8) {
      int cc[8], aa[8];
      float xx[8];
#pragma unroll
      for (int q = 0; q < 8; ++q) {
        cc[q] = __shfl(p.x, j + q, 32);
        aa[q] = __shfl(p.y, j + q, 32);
      }
#pragma unroll
      for (int q = 0; q < 8; ++q) xx[q] = embeds[(size_t)cc[q] * DD + d];
#pragma unroll
      for (int q = 0; q < 8; ++q)
        acc = __fadd_rn(acc, __fmul_rn(__int_as_float(aa[q]), xx[q]));
    }
  }
  e0[(size_t)r * DD + d] = __fsub_rn(acc, embeds[(size_t)r * DD + d]);
}

// FUSED emb+num step (lane d==0 writes num outputs)
// mode: 1 = sums init, write next; 2 = sums +=, write next; 3 = sums += only
__global__ void k_emb_step(const int* __restrict__ rp, const int2* __restrict__ pk,
                           const float* __restrict__ ord, const float* __restrict__ ecur,
                           float* __restrict__ enext, float* __restrict__ esum,
                           const float* __restrict__ ncur, float* __restrict__ nnext,
                           float* __restrict__ nsum, int mode) {
  int tid = blockIdx.x * blockDim.x + threadIdx.x;
  int r = tid >> 5, d = tid & 31;
  if (r >= NN) return;
  int s = rp[r], t = rp[r + 1];
  float acc = 0.0f, accn = 0.0f;
  for (int base = s; base < t; base += 32) {
    int idx = base + d;
    int2 p = (idx < t) ? pk[idx] : make_int2(0, 0);
    int m = t - base; if (m > 32) m = 32;
    for (int j = 0; j < m; j += 8) {
      int cc[8], aa[8];
      float xx[8], nn[8];
#pragma unroll
      for (int q = 0; q < 8; ++q) {
        cc[q] = __shfl(p.x, j + q, 32);
        aa[q] = __shfl(p.y, j + q, 32);
      }
#pragma unroll
      for (int q = 0; q < 8; ++q) {
        xx[q] = ecur[(size_t)cc[q] * DD + d];
        nn[q] = ncur[cc[q]];
      }
#pragma unroll
      for (int q = 0; q < 8; ++q) {
        float av = __int_as_float(aa[q]);
        acc = __fadd_rn(acc, __fmul_rn(av, xx[q]));
        accn = __fadd_rn(accn, __fmul_rn(av, nn[q]));
      }
    }
  }
  float ordv = ord[r];
  size_t idx = (size_t)r * DD + d;
  float ec = ecur[idx];
  float o = __fsub_rn(__fsub_rn(acc, ec), __fmul_rn(ordv, ec));
  if (mode != 3) enext[idx] = o;
  if (mode == 1) esum[idx] = __fadd_rn(ec, o);
  else esum[idx] = __fadd_rn(esum[idx], o);
  if (d == 0) {
    float nc = ncur[r];
    float on = __fsub_rn(__fsub_rn(accn, nc), ordv);
    if (mode != 3) nnext[r] = on;
    if (mode == 1) nsum[r] = __fadd_rn(nc, on);
    else nsum[r] = __fadd_rn(nsum[r], on);
  }
}

__global__ void k_final(const float* __restrict__ embeds, const float* __restrict__ emb_sum,
                        const float* __restrict__ num_sum, uint32_t gk0, uint32_t gk1,
                        float* __restrict__ out_scores, int* __restrict__ hist) {
  int r = blockIdx.x * blockDim.x + threadIdx.x;
  if (r >= NN) return;
  float denom = __fadd_rn(num_sum[r], 1e-8f);
  float sub[DD], em[DD], pr[DD];
  const float4* ps = (const float4*)(emb_sum + (size_t)r * DD);
  const float4* pe = (const float4*)(embeds + (size_t)r * DD);
#pragma unroll
  for (int j = 0; j < 8; ++j) {
    float4 a = ps[j], b = pe[j];
    sub[4 * j + 0] = __fdiv_rn(a.x, denom); sub[4 * j + 1] = __fdiv_rn(a.y, denom);
    sub[4 * j + 2] = __fdiv_rn(a.z, denom); sub[4 * j + 3] = __fdiv_rn(a.w, denom);
    em[4 * j + 0] = b.x; em[4 * j + 1] = b.y; em[4 * j + 2] = b.z; em[4 * j + 3] = b.w;
  }
#pragma unroll
  for (int d = 0; d < DD; ++d) pr[d] = __fmul_rn(sub[d], sub[d]);
  float n1 = fmaxf(__fsqrt_rn(pairwise32(pr)), 1e-12f);
#pragma unroll
  for (int d = 0; d < DD; ++d) pr[d] = __fmul_rn(em[d], em[d]);
  float n2 = fmaxf(__fsqrt_rn(pairwise32(pr)), 1e-12f);
#pragma unroll
  for (int d = 0; d < DD; ++d)
    pr[d] = __fmul_rn(__fdiv_rn(sub[d], n1), __fdiv_rn(em[d], n2));
  float dot = pairwise32(pr);
  float u = bits_to_uniform(jax_bits32(gk0, gk1, (uint32_t)r));
  float l1 = (float)log((double)u);
  float w = -l1;
  float l2 = (float)log((double)w);
  float g = -l2;
  float score = __fadd_rn(dot, g);
  out_scores[r] = score;
  uint32_t kb = __float_as_uint(score);
  kb = (kb & 0x80000000u) ? ~kb : (kb | 0x80000000u);
  atomicAdd(&hist[kb >> 16], 1);
}

__global__ void k_cutoff(const int* __restrict__ hist, int* __restrict__ cutoff) {
  __shared__ int psum[1024];
  int t = threadIdx.x;
  int base = HSIZE - (t + 1) * 64;
  int own = 0;
  for (int i = 0; i < 64; ++i) own += hist[base + i];
  psum[t] = own;
  __syncthreads();
  for (int off = 1; off < 1024; off <<= 1) {
    int v = (t >= off) ? psum[t - off] : 0;
    __syncthreads();
    psum[t] += v;
    __syncthreads();
  }
  int incl = psum[t];
  int prev = incl - own;
  if (incl >= NCAND && prev < NCAND) {
    int c = prev;
    int b = HSIZE - t * 64 - 1;
    while (b >= base) {
      c += hist[b];
      if (c >= NCAND) break;
      --b;
    }
    *cutoff = b;
  }
}

__global__ void k_collect(const float* __restrict__ scores, const int* __restrict__ cutoff,
                          unsigned long long* __restrict__ buf, int* __restrict__ cnt2) {
  int r = blockIdx.x * blockDim.x + threadIdx.x;
  if (r >= NN) return;
  uint32_t kb = __float_as_uint(scores[r]);
  kb = (kb & 0x80000000u) ? ~kb : (kb | 0x80000000u);
  if ((int)(kb >> 16) >= *cutoff) {
    int p = atomicAdd(cnt2, 1);
    if (p < SORTN)
      buf[p] = ((unsigned long long)kb << 32) | (uint32_t)(~(uint32_t)r);
  }
}

__global__ __launch_bounds__(1024) void k_sort(const unsigned long long* __restrict__ buf,
                                               const int* __restrict__ cnt2,
                                               float* __restrict__ out_cand) {
  __shared__ unsigned long long s[SORTN];
  int m = *cnt2;
  if (m > SORTN) m = SORTN;
  for (int i = threadIdx.x; i < SORTN; i += 1024) s[i] = (i < m) ? buf[i] : 0ull;
  __syncthreads();
  for (int k = 2; k <= SORTN; k <<= 1) {
    for (int j = k >> 1; j > 0; j >>= 1) {
      for (int i = threadIdx.x; i < SORTN; i += 1024) {
        int ixj = i ^ j;
        if (ixj > i) {
          unsigned long long a = s[i], b = s[ixj];
          bool desc = ((i & k) == 0);
          if (desc ? (a < b) : (a > b)) { s[i] = b; s[ixj] = a; }
        }
      }
      __syncthreads();
    }
  }
  for (int i = threadIdx.x; i < NCAND; i += 1024) {
    uint32_t idx = ~((uint32_t)(s[i] & 0xffffffffull));
    out_cand[i] = (float)idx;
  }
}

// ---------------- host ----------------
extern "C" void kernel_launch(void* const* d_in, const int* in_sizes, int n_in,
                              void* d_out, int out_size, void* d_ws, size_t ws_size,
                              hipStream_t stream) {
  const int* rows = (const int*)d_in[0];
  const int* cols = rows + NE;
  const float* adj = (const float*)d_in[1];
  const float* embeds = (const float*)d_in[2];
  float* out = (float*)d_out;

  char* p = (char*)d_ws;
  auto alloc = [&](size_t bytes) {
    char* q = p;
    p += (bytes + 255) & ~(size_t)255;
    return q;
  };
  size_t zero_bytes = (size_t)(5 * NBUK + HSIZE + 8) * 4;
  char* zero_base = (char*)alloc(zero_bytes);
  int* bucketCursor = (int*)zero_base;
  int* bucketCntS = bucketCursor + NBUK;
  int* hist = bucketCntS + 4 * NBUK;
  int* cnt2 = hist + HSIZE;  // [0]=collect count, [1]=cutoff bin

  int* bucketBaseS = (int*)alloc((size_t)4 * (NBUK + 1) * 4);
  int* rpAll = (int*)alloc((size_t)4 * (NN + 1) * 4);
  // padded pkBin (32 MB) dead after kB_emit; embA/embB overlay it
  size_t padBytes = (size_t)NBUK * BCAP * 16;
  char* unionAB = (char*)alloc(padBytes);
  int4* pkBin = (int4*)unionAB;
  float* embA = (float*)unionAB;                           // 12.8 MB
  float* embB = (float*)(unionAB + (size_t)NN * DD * 4);   // 12.8 MB
  int2* pk0 = (int2*)alloc((size_t)NE * 8);
  int2* pk1 = (int2*)alloc((size_t)CAP1 * 8);
  int2* pk2 = (int2*)alloc((size_t)CAP2 * 8);
  int2* pk3 = (int2*)alloc((size_t)CAP3 * 8);
  float* embS = (float*)alloc((size_t)NN * DD * 4);
  float* order0 = (float*)alloc(NN * 4);
  float* order1 = (float*)alloc(NN * 4);
  float* order2 = (float*)alloc(NN * 4);
  float* num1 = (float*)alloc(NN * 4);
  float* num2 = (float*)alloc(NN * 4);
  float* numS = (float*)alloc(NN * 4);
  unsigned long long* buf = (unsigned long long*)alloc(SORTN * 8);

  uint32_t dk[3][2];
  for (int i = 0; i < 3; ++i) tf2x32(0u, 42u, 0u, (uint32_t)i, dk[i][0], dk[i][1]);

  hipMemsetAsync(zero_base, 0, zero_bytes, stream);

  int gE = (NE + EPB - 1) / EPB;  // 391
  kA2_bin<<<gE, 512, 0, stream>>>(rows, cols, adj, dk[0][0], dk[0][1], dk[1][0], dk[1][1],
                                  dk[2][0], dk[2][1], bucketCursor, pkBin, bucketCntS);
  k_scanBS<<<4, 512, 0, stream>>>(bucketCntS, bucketBaseS);
  kB_emit<<<NBUK, 512, 0, stream>>>(bucketBaseS, pkBin, rpAll,
                                    pk0, pk1, pk2, pk3, order0, order1, order2);

  const int* rp0 = rpAll;
  const int* rp1 = rpAll + (NN + 1);
  const int* rp2 = rpAll + 2 * (NN + 1);
  const int* rp3 = rpAll + 3 * (NN + 1);

  int gEmb = (NN * 32 + 255) / 256;
  k_emb0<<<gEmb, 256, 0, stream>>>(rp0, pk0, embeds, embA);

  // stage 1: emb cur=embA -> next=embB, num cur=order0 -> num1, sums init
  k_emb_step<<<gEmb, 256, 0, stream>>>(rp1, pk1, order0, embA, embB, embS,
                                       order0, num1, numS, 1);
  // stage 2: emb cur=embB -> next=embA, num cur=num1 -> num2, sums +=
  k_emb_step<<<gEmb, 256, 0, stream>>>(rp2, pk2, order1, embB, embA, embS,
                                       num1, num2, numS, 2);
  // stage 3: sums += only
  k_emb_step<<<gEmb, 256, 0, stream>>>(rp3, pk3, order2, embA, embB, embS,
                                       num2, num1, numS, 3);

  k_final<<<(NN + 255) / 256, 256, 0, stream>>>(embeds, embS, numS, 0u, 7u, out, hist);
  k_cutoff<<<1, 1024, 0, stream>>>(hist, cnt2 + 1);
  k_collect<<<(NN + 255) / 256, 256, 0, stream>>>(out, cnt2 + 1, buf, cnt2);
  k_sort<<<1, 1024, 0, stream>>>(buf, cnt2, out + NN);
}

// Round 16
// 382.535 us; speedup vs baseline: 1.2075x; 1.0246x over previous
//
#include <hip/hip_runtime.h>
#include <stdint.h>
#include <stddef.h>

#define NN 100000
#define NE 1600000
#define DD 32
#define NCAND 1024
#define HSIZE 65536
#define SORTN 4096
#define NBUK ((NN + 255) / 256)            // 391 buckets of 256 rows
#define EPB 4096                           // edges per block in kA2
#define BCAP 5120                          // padded bucket capacity

// capacity for per-stage packed lists (mean + huge margin)
#define CAP1 832000
#define CAP2 432000
#define CAP3 240000

// ---------------- JAX threefry2x32 (20 rounds) ----------------
__host__ __device__ inline void tf2x32(uint32_t k0, uint32_t k1, uint32_t x0, uint32_t x1,
                                       uint32_t& o0, uint32_t& o1) {
  uint32_t ks2 = k0 ^ k1 ^ 0x1BD11BDAu;
  uint32_t v0 = x0 + k0, v1 = x1 + k1;
#define TFR(r) { v0 += v1; v1 = (v1 << (r)) | (v1 >> (32 - (r))); v1 ^= v0; }
  TFR(13) TFR(15) TFR(26) TFR(6)   v0 += k1;  v1 += ks2 + 1u;
  TFR(17) TFR(29) TFR(16) TFR(24)  v0 += ks2; v1 += k0 + 2u;
  TFR(13) TFR(15) TFR(26) TFR(6)   v0 += k0;  v1 += k1 + 3u;
  TFR(17) TFR(29) TFR(16) TFR(24)  v0 += k1;  v1 += ks2 + 4u;
  TFR(13) TFR(15) TFR(26) TFR(6)   v0 += ks2; v1 += k0 + 5u;
#undef TFR
  o0 = v0; o1 = v1;
}

__device__ __forceinline__ uint32_t jax_bits32(uint32_t k0, uint32_t k1, uint32_t i) {
  uint32_t o0, o1;
  tf2x32(k0, k1, 0u, i, o0, o1);
  return o0 ^ o1;
}

__device__ __forceinline__ float bits_to_uniform(uint32_t b) {
  return __fsub_rn(__uint_as_float((b >> 9) | 0x3f800000u), 1.0f);
}

// numpy-pairwise sum of 32 floats
__device__ __forceinline__ float pairwise32(const float* x) {
  float r[8];
#pragma unroll
  for (int j = 0; j < 8; ++j) r[j] = x[j];
#pragma unroll
  for (int b = 8; b < 32; b += 8)
#pragma unroll
    for (int j = 0; j < 8; ++j) r[j] = __fadd_rn(r[j], x[b + j]);
  float a01 = __fadd_rn(r[0], r[1]), a23 = __fadd_rn(r[2], r[3]);
  float a45 = __fadd_rn(r[4], r[5]), a67 = __fadd_rn(r[6], r[7]);
  return __fadd_rn(__fadd_rn(a01, a23), __fadd_rn(a45, a67));
}

// ---------------- preprocessing ----------------

__global__ __launch_bounds__(512) void kA2_bin(
    const int* __restrict__ rows, const int* __restrict__ cols,
    const float* __restrict__ adj,
    uint32_t k00, uint32_t k01, uint32_t k10, uint32_t k11,
    uint32_t k20, uint32_t k21,
    int* __restrict__ bucketCursor, int4* __restrict__ pkBin,
    int* __restrict__ bucketCntS) {
  __shared__ int hist[NBUK];
  __shared__ int base[NBUK];
  __shared__ int h1[NBUK];
  __shared__ int h2[NBUK];
  __shared__ int h3[NBUK];
  __shared__ uint8_t lvs[EPB];
  __shared__ uint16_t rank16[EPB];
  int tid = threadIdx.x;
  for (int i = tid; i < NBUK; i += 512) { hist[i] = 0; h1[i] = 0; h2[i] = 0; h3[i] = 0; }
  __syncthreads();
  int e0 = blockIdx.x * EPB;
  for (int k = 0; k < 8; ++k) {
    int e = e0 + k * 512 + tid;
    int lv = 0;
    if (e < NE) {
      float u0 = bits_to_uniform(jax_bits32(k00, k01, (uint32_t)e));
      float u1 = bits_to_uniform(jax_bits32(k10, k11, (uint32_t)e));
      float u2 = bits_to_uniform(jax_bits32(k20, k21, (uint32_t)e));
      float kp0 = floorf(__fadd_rn(u0, 0.5f));
      float kp1 = floorf(__fadd_rn(u1, 0.25f));
      float kp2 = floorf(__fadd_rn(u2, 0.125f));
      if (kp0 != 0.0f) { lv = 1; if (kp1 != 0.0f) { lv = 2; if (kp2 != 0.0f) lv = 3; } }
      int b = rows[e] >> 8;
      rank16[k * 512 + tid] = (uint16_t)atomicAdd(&hist[b], 1);
      if (lv >= 1) {
        atomicAdd(&h1[b], 1);
        if (lv >= 2) {
          atomicAdd(&h2[b], 1);
          if (lv >= 3) atomicAdd(&h3[b], 1);
        }
      }
    }
    lvs[k * 512 + tid] = (uint8_t)lv;
  }
  __syncthreads();
  for (int i = tid; i < NBUK; i += 512) {
    int h = hist[i];
    base[i] = (h > 0) ? atomicAdd(&bucketCursor[i], h) : 0;
    if (h) atomicAdd(&bucketCntS[i], h);
    if (h1[i]) atomicAdd(&bucketCntS[NBUK + i], h1[i]);
    if (h2[i]) atomicAdd(&bucketCntS[2 * NBUK + i], h2[i]);
    if (h3[i]) atomicAdd(&bucketCntS[3 * NBUK + i], h3[i]);
  }
  __syncthreads();
  for (int k = 0; k < 8; ++k) {
    int e = e0 + k * 512 + tid;
    if (e < NE) {
      int r = rows[e];
      int b = r >> 8;
      int lv = (int)lvs[k * 512 + tid];
      int pos = base[b] + (int)rank16[k * 512 + tid];
      if (pos < BCAP)  // overflow guard (P~0)
        pkBin[(size_t)b * BCAP + pos] =
            make_int4(cols[e], __float_as_int(adj[e]), (e << 2) | lv, r);
    }
  }
}

__global__ __launch_bounds__(512) void k_scanBS(const int* __restrict__ bucketCntS,
                                                int* __restrict__ bucketBaseS) {
  __shared__ int sb[512];
  int a = blockIdx.x;
  const int* c = bucketCntS + (size_t)a * NBUK;
  int* o = bucketBaseS + (size_t)a * (NBUK + 1);
  int tid = threadIdx.x;
  int v = (tid < NBUK) ? c[tid] : 0;
  sb[tid] = v;
  __syncthreads();
  for (int off = 1; off < 512; off <<= 1) {
    int x = (tid >= off) ? sb[tid - off] : 0;
    __syncthreads();
    sb[tid] += x;
    __syncthreads();
  }
  if (tid < NBUK) o[tid] = sb[tid] - v;
  if (tid == NBUK - 1) o[NBUK] = sb[tid];
}

// per-bucket: ONE global pass stashes key+payload in LDS; group, parallel
// rank-by-counting sort, order sums, and coalesced emit all run from LDS.
__global__ __launch_bounds__(512) void kB_emit(
    const int* __restrict__ bucketBaseS, const int4* __restrict__ pkBin,
    int* __restrict__ rpAll,
    int2* __restrict__ pk0, int2* __restrict__ pk1,
    int2* __restrict__ pk2, int2* __restrict__ pk3,
    float* __restrict__ order0, float* __restrict__ order1, float* __restrict__ order2) {
  __shared__ unsigned long long cnt64[256];
  __shared__ unsigned long long sb64[256];
  __shared__ unsigned long long ps64[512];
  __shared__ int start0[256];
  __shared__ int cur[256];
  __shared__ uint32_t keyF[BCAP];   // (lr<<23)|(eid<<2)|lv  (31 bits)
  __shared__ int2 payL[BCAP];       // (col, adj_bits)
  __shared__ uint16_t origG[BCAP];  // grouped slot -> original index (sorted in place)
  int b = blockIdx.x, tid = threadIdx.x;
  int bB0 = bucketBaseS[b];
  int n = bucketBaseS[b + 1] - bB0;
  if (n > BCAP) n = BCAP;  // LDS-safety clamp (P~0)
  size_t sRead = (size_t)b * BCAP;
  int r0 = b << 8;
  int nr = NN - r0; if (nr > 256) nr = 256;
  int bB1 = bucketBaseS[(NBUK + 1) + b];
  int bB2 = bucketBaseS[2 * (NBUK + 1) + b];
  int bB3 = bucketBaseS[3 * (NBUK + 1) + b];
  if (tid < 256) { cnt64[tid] = 0ull; cur[tid] = 0; }
  __syncthreads();
  // single global pass: load, stash, count
  for (int i = tid; i < n; i += 512) {
    int4 p = pkBin[sRead + i];
    int lr = p.w - r0;
    int lv = p.z & 3;
    keyF[i] = ((uint32_t)lr << 23) | (uint32_t)p.z;
    payL[i] = make_int2(p.x, p.y);
    unsigned long long add = 1ull;
    if (lv >= 1) add |= 1ull << 16;
    if (lv >= 2) add |= 1ull << 32;
    if (lv >= 3) add |= 1ull << 48;
    atomicAdd(&cnt64[lr], add);
  }
  __syncthreads();
  unsigned long long own = (tid < 256) ? cnt64[tid] : 0ull;
  if (tid < 256) sb64[tid] = own;
  __syncthreads();
  for (int off = 1; off < 256; off <<= 1) {
    unsigned long long v = (tid < 256 && tid >= off) ? sb64[tid - off] : 0ull;
    __syncthreads();
    if (tid < 256) sb64[tid] += v;
    __syncthreads();
  }
  if (tid < 256) {
    unsigned long long ex = sb64[tid] - own;
    start0[tid] = (int)(ex & 0xFFFFull);
    if (tid < nr) {
      rpAll[r0 + tid] = bB0 + (int)(ex & 0xFFFFull);
      rpAll[(NN + 1) + r0 + tid] = bB1 + (int)((ex >> 16) & 0xFFFFull);
      rpAll[2 * (NN + 1) + r0 + tid] = bB2 + (int)((ex >> 32) & 0xFFFFull);
      rpAll[3 * (NN + 1) + r0 + tid] = bB3 + (int)((ex >> 48) & 0xFFFFull);
    }
  }
  if (b == NBUK - 1 && tid == 0) {
    rpAll[NN] = bucketBaseS[NBUK];
    rpAll[(NN + 1) + NN] = bucketBaseS[(NBUK + 1) + NBUK];
    rpAll[2 * (NN + 1) + NN] = bucketBaseS[2 * (NBUK + 1) + NBUK];
    rpAll[3 * (NN + 1) + NN] = bucketBaseS[3 * (NBUK + 1) + NBUK];
  }
  __syncthreads();
  // group (LDS->LDS)
  for (int i = tid; i < n; i += 512) {
    int lr = (int)(keyF[i] >> 23);
    int slot = start0[lr] + atomicAdd(&cur[lr], 1);
    origG[slot] = (uint16_t)i;
  }
  __syncthreads();
  // parallel rank-by-counting sort of each row segment (keys unique ->
  // ranks are a permutation). Read phase / register stage / write phase.
  {
    int C2 = (n + 511) >> 9;  // <= 10
    int lo2 = tid * C2, hi2 = lo2 + C2;
    if (lo2 > n) lo2 = n;
    if (hi2 > n) hi2 = n;
    uint16_t vals[10];
    uint16_t pos[10];
    int cntE = 0;
    for (int i = lo2; i < hi2; ++i) {
      uint16_t ov = origG[i];
      uint32_t ki = keyF[ov];
      int lr = (int)(ki >> 23);
      int st = start0[lr];
      int d = (int)(cnt64[lr] & 0xFFFFull);
      int rank = 0;
      for (int j = 0; j < d; ++j) {
        uint32_t kj = keyF[origG[st + j]];
        rank += (kj < ki) ? 1 : 0;
      }
      vals[cntE] = ov;
      pos[cntE] = (uint16_t)(st + rank);
      ++cntE;
    }
    __syncthreads();
    for (int q = 0; q < cntE; ++q) origG[pos[q]] = vals[q];
  }
  __syncthreads();
  // orders in sorted (reference) order — all LDS
  if (tid < nr) {
    int d = (int)(cnt64[tid] & 0xFFFFull);
    int st = start0[tid];
    float o0 = 0.0f, o1v = 0.0f, o2v = 0.0f;
    for (int i = 0; i < d; ++i) {
      uint16_t o = origG[st + i];
      int lv = (int)(keyF[o] & 3u);
      float a = __int_as_float(payL[o].y);
      o0 = __fadd_rn(o0, a);
      if (lv >= 1) { o1v = __fadd_rn(o1v, a); if (lv >= 2) o2v = __fadd_rn(o2v, a); }
    }
    order0[r0 + tid] = o0; order1[r0 + tid] = o1v; order2[r0 + tid] = o2v;
  }
  // chunked block scan of stage flags + coalesced emit — all LDS
  int C = (n + 511) >> 9;
  int lo = tid * C, hi = lo + C;
  if (lo > n) lo = n;
  if (hi > n) hi = n;
  int c1 = 0, c2 = 0, c3 = 0;
  for (int i = lo; i < hi; ++i) {
    int lv = (int)(keyF[origG[i]] & 3u);
    c1 += (lv >= 1); c2 += (lv >= 2); c3 += (lv >= 3);
  }
  unsigned long long mine = (unsigned long long)c1 |
                            ((unsigned long long)c2 << 16) |
                            ((unsigned long long)c3 << 32);
  ps64[tid] = mine;
  __syncthreads();
  for (int off = 1; off < 512; off <<= 1) {
    unsigned long long v = (tid >= off) ? ps64[tid - off] : 0ull;
    __syncthreads();
    ps64[tid] += v;
    __syncthreads();
  }
  unsigned long long ex = ps64[tid] - mine;
  int o1 = bB1 + (int)(ex & 0xFFFFull);
  int o2 = bB2 + (int)((ex >> 16) & 0xFFFFull);
  int o3 = bB3 + (int)((ex >> 32) & 0xFFFFull);
  for (int i = lo; i < hi; ++i) {
    uint16_t o = origG[i];
    int lv = (int)(keyF[o] & 3u);
    int2 pkv = payL[o];
    pk0[bB0 + i] = pkv;  // sequential within bucket
    if (lv >= 1) {
      pk1[o1++] = pkv;
      if (lv >= 2) {
        pk2[o2++] = pkv;
        if (lv >= 3) pk3[o3++] = pkv;
      }
    }
  }
}

// ---------------- SpMM chain: 8-deep software-pipelined gathers ----------------

// fst_emb = spmm(adj, embeds) - embeds
__global__ void k_emb0(const int* __restrict__ rp, const int2* __restrict__ pk,
                       const float* __restrict__ embeds, float* __restrict__ e0) {
  int tid = blockIdx.x * blockDim.x + threadIdx.x;
  int r = tid >> 5, d = tid & 31;
  if (r >= NN) return;
  int s = rp[r], t = rp[r + 1];
  float acc = 0.0f;
  for (int base = s; base < t; base += 32) {
    int idx = base + d;
    int2 p = (idx < t) ? pk[idx] : make_int2(0, 0);
    int m = t - base; if (m > 32) m = 32;
    for (int j = 0; j < m; j += 8) {
      int cc[8], aa[8];
      float xx[8];
#pragma unroll
      for (int q = 0; q < 8; ++q) {
        cc[q] = __shfl(p.x, j + q, 32);
        aa[q] = __shfl(p.y, j + q, 32);
      }
#pragma unroll
      for (int q = 0; q < 8; ++q) xx[q] = embeds[(size_t)cc[q] * DD + d];
#pragma unroll
      for (int q = 0; q < 8; ++q)
        acc = __fadd_rn(acc, __fmul_rn(__int_as_float(aa[q]), xx[q]));
    }
  }
  e0[(size_t)r * DD + d] = __fsub_rn(acc, embeds[(size_t)r * DD + d]);
}

// FUSED emb+num step (lane d==0 writes num outputs)
// mode: 1 = sums init, write next; 2 = sums +=, write next; 3 = sums += only
__global__ void k_emb_step(const int* __restrict__ rp, const int2* __restrict__ pk,
                           const float* __restrict__ ord, const float* __restrict__ ecur,
                           float* __restrict__ enext, float* __restrict__ esum,
                           const float* __restrict__ ncur, float* __restrict__ nnext,
                           float* __restrict__ nsum, int mode) {
  int tid = blockIdx.x * blockDim.x + threadIdx.x;
  int r = tid >> 5, d = tid & 31;
  if (r >= NN) return;
  int s = rp[r], t = rp[r + 1];
  float acc = 0.0f, accn = 0.0f;
  for (int base = s; base < t; base += 32) {
    int idx = base + d;
    int2 p = (idx < t) ? pk[idx] : make_int2(0, 0);
    int m = t - base; if (m > 32) m = 32;
    for (int j = 0; j < m; j += 8) {
      int cc[8], aa[8];
      float xx[8], nn[8];
#pragma unroll
      for (int q = 0; q < 8; ++q) {
        cc[q] = __shfl(p.x, j + q, 32);
        aa[q] = __shfl(p.y, j + q, 32);
      }
#pragma unroll
      for (int q = 0; q < 8; ++q) {
        xx[q] = ecur[(size_t)cc[q] * DD + d];
        nn[q] = ncur[cc[q]];
      }
#pragma unroll
      for (int q = 0; q < 8; ++q) {
        float av = __int_as_float(aa[q]);
        acc = __fadd_rn(acc, __fmul_rn(av, xx[q]));
        accn = __fadd_rn(accn, __fmul_rn(av, nn[q]));
      }
    }
  }
  float ordv = ord[r];
  size_t idx = (size_t)r * DD + d;
  float ec = ecur[idx];
  float o = __fsub_rn(__fsub_rn(acc, ec), __fmul_rn(ordv, ec));
  if (mode != 3) enext[idx] = o;
  if (mode == 1) esum[idx] = __fadd_rn(ec, o);
  else esum[idx] = __fadd_rn(esum[idx], o);
  if (d == 0) {
    float nc = ncur[r];
    float on = __fsub_rn(__fsub_rn(accn, nc), ordv);
    if (mode != 3) nnext[r] = on;
    if (mode == 1) nsum[r] = __fadd_rn(nc, on);
    else nsum[r] = __fadd_rn(nsum[r], on);
  }
}

__global__ void k_final(const float* __restrict__ embeds, const float* __restrict__ emb_sum,
                        const float* __restrict__ num_sum, uint32_t gk0, uint32_t gk1,
                        float* __restrict__ out_scores, int* __restrict__ hist) {
  int r = blockIdx.x * blockDim.x + threadIdx.x;
  if (r >= NN) return;
  float denom = __fadd_rn(num_sum[r], 1e-8f);
  float sub[DD], em[DD], pr[DD];
  const float4* ps = (const float4*)(emb_sum + (size_t)r * DD);
  const float4* pe = (const float4*)(embeds + (size_t)r * DD);
#pragma unroll
  for (int j = 0; j < 8; ++j) {
    float4 a = ps[j], b = pe[j];
    sub[4 * j + 0] = __fdiv_rn(a.x, denom); sub[4 * j + 1] = __fdiv_rn(a.y, denom);
    sub[4 * j + 2] = __fdiv_rn(a.z, denom); sub[4 * j + 3] = __fdiv_rn(a.w, denom);
    em[4 * j + 0] = b.x; em[4 * j + 1] = b.y; em[4 * j + 2] = b.z; em[4 * j + 3] = b.w;
  }
#pragma unroll
  for (int d = 0; d < DD; ++d) pr[d] = __fmul_rn(sub[d], sub[d]);
  float n1 = fmaxf(__fsqrt_rn(pairwise32(pr)), 1e-12f);
#pragma unroll
  for (int d = 0; d < DD; ++d) pr[d] = __fmul_rn(em[d], em[d]);
  float n2 = fmaxf(__fsqrt_rn(pairwise32(pr)), 1e-12f);
#pragma unroll
  for (int d = 0; d < DD; ++d)
    pr[d] = __fmul_rn(__fdiv_rn(sub[d], n1), __fdiv_rn(em[d], n2));
  float dot = pairwise32(pr);
  float u = bits_to_uniform(jax_bits32(gk0, gk1, (uint32_t)r));
  float l1 = (float)log((double)u);
  float w = -l1;
  float l2 = (float)log((double)w);
  float g = -l2;
  float score = __fadd_rn(dot, g);
  out_scores[r] = score;
  uint32_t kb = __float_as_uint(score);
  kb = (kb & 0x80000000u) ? ~kb : (kb | 0x80000000u);
  atomicAdd(&hist[kb >> 16], 1);
}

__global__ void k_cutoff(const int* __restrict__ hist, int* __restrict__ cutoff) {
  __shared__ int psum[1024];
  int t = threadIdx.x;
  int base = HSIZE - (t + 1) * 64;
  int own = 0;
  for (int i = 0; i < 64; ++i) own += hist[base + i];
  psum[t] = own;
  __syncthreads();
  for (int off = 1; off < 1024; off <<= 1) {
    int v = (t >= off) ? psum[t - off] : 0;
    __syncthreads();
    psum[t] += v;
    __syncthreads();
  }
  int incl = psum[t];
  int prev = incl - own;
  if (incl >= NCAND && prev < NCAND) {
    int c = prev;
    int b = HSIZE - t * 64 - 1;
    while (b >= base) {
      c += hist[b];
      if (c >= NCAND) break;
      --b;
    }
    *cutoff = b;
  }
}

__global__ void k_collect(const float* __restrict__ scores, const int* __restrict__ cutoff,
                          unsigned long long* __restrict__ buf, int* __restrict__ cnt2) {
  int r = blockIdx.x * blockDim.x + threadIdx.x;
  if (r >= NN) return;
  uint32_t kb = __float_as_uint(scores[r]);
  kb = (kb & 0x80000000u) ? ~kb : (kb | 0x80000000u);
  if ((int)(kb >> 16) >= *cutoff) {
    int p = atomicAdd(cnt2, 1);
    if (p < SORTN)
      buf[p] = ((unsigned long long)kb << 32) | (uint32_t)(~(uint32_t)r);
  }
}

__global__ __launch_bounds__(1024) void k_sort(const unsigned long long* __restrict__ buf,
                                               const int* __restrict__ cnt2,
                                               float* __restrict__ out_cand) {
  __shared__ unsigned long long s[SORTN];
  int m = *cnt2;
  if (m > SORTN) m = SORTN;
  for (int i = threadIdx.x; i < SORTN; i += 1024) s[i] = (i < m) ? buf[i] : 0ull;
  __syncthreads();
  for (int k = 2; k <= SORTN; k <<= 1) {
    for (int j = k >> 1; j > 0; j >>= 1) {
      for (int i = threadIdx.x; i < SORTN; i += 1024) {
        int ixj = i ^ j;
        if (ixj > i) {
          unsigned long long a = s[i], b = s[ixj];
          bool desc = ((i & k) == 0);
          if (desc ? (a < b) : (a > b)) { s[i] = b; s[ixj] = a; }
        }
      }
      __syncthreads();
    }
  }
  for (int i = threadIdx.x; i < NCAND; i += 1024) {
    uint32_t idx = ~((uint32_t)(s[i] & 0xffffffffull));
    out_cand[i] = (float)idx;
  }
}

// ---------------- host ----------------
extern "C" void kernel_launch(void* const* d_in, const int* in_sizes, int n_in,
                              void* d_out, int out_size, void* d_ws, size_t ws_size,
                              hipStream_t stream) {
  const int* rows = (const int*)d_in[0];
  const int* cols = rows + NE;
  const float* adj = (const float*)d_in[1];
  const float* embeds = (const float*)d_in[2];
  float* out = (float*)d_out;

  char* p = (char*)d_ws;
  auto alloc = [&](size_t bytes) {
    char* q = p;
    p += (bytes + 255) & ~(size_t)255;
    return q;
  };
  size_t zero_bytes = (size_t)(5 * NBUK + HSIZE + 8) * 4;
  char* zero_base = (char*)alloc(zero_bytes);
  int* bucketCursor = (int*)zero_base;
  int* bucketCntS = bucketCursor + NBUK;
  int* hist = bucketCntS + 4 * NBUK;
  int* cnt2 = hist + HSIZE;  // [0]=collect count, [1]=cutoff bin

  int* bucketBaseS = (int*)alloc((size_t)4 * (NBUK + 1) * 4);
  int* rpAll = (int*)alloc((size_t)4 * (NN + 1) * 4);
  // padded pkBin (32 MB) dead after kB_emit; embA/embB overlay it
  size_t padBytes = (size_t)NBUK * BCAP * 16;
  char* unionAB = (char*)alloc(padBytes);
  int4* pkBin = (int4*)unionAB;
  float* embA = (float*)unionAB;                           // 12.8 MB
  float* embB = (float*)(unionAB + (size_t)NN * DD * 4);   // 12.8 MB
  int2* pk0 = (int2*)alloc((size_t)NE * 8);
  int2* pk1 = (int2*)alloc((size_t)CAP1 * 8);
  int2* pk2 = (int2*)alloc((size_t)CAP2 * 8);
  int2* pk3 = (int2*)alloc((size_t)CAP3 * 8);
  float* embS = (float*)alloc((size_t)NN * DD * 4);
  float* order0 = (float*)alloc(NN * 4);
  float* order1 = (float*)alloc(NN * 4);
  float* order2 = (float*)alloc(NN * 4);
  float* num1 = (float*)alloc(NN * 4);
  float* num2 = (float*)alloc(NN * 4);
  float* numS = (float*)alloc(NN * 4);
  unsigned long long* buf = (unsigned long long*)alloc(SORTN * 8);

  uint32_t dk[3][2];
  for (int i = 0; i < 3; ++i) tf2x32(0u, 42u, 0u, (uint32_t)i, dk[i][0], dk[i][1]);

  hipMemsetAsync(zero_base, 0, zero_bytes, stream);

  int gE = (NE + EPB - 1) / EPB;  // 391
  kA2_bin<<<gE, 512, 0, stream>>>(rows, cols, adj, dk[0][0], dk[0][1], dk[1][0], dk[1][1],
                                  dk[2][0], dk[2][1], bucketCursor, pkBin, bucketCntS);
  k_scanBS<<<4, 512, 0, stream>>>(bucketCntS, bucketBaseS);
  kB_emit<<<NBUK, 512, 0, stream>>>(bucketBaseS, pkBin, rpAll,
                                    pk0, pk1, pk2, pk3, order0, order1, order2);

  const int* rp0 = rpAll;
  const int* rp1 = rpAll + (NN + 1);
  const int* rp2 = rpAll + 2 * (NN + 1);
  const int* rp3 = rpAll + 3 * (NN + 1);

  int gEmb = (NN * 32 + 255) / 256;
  k_emb0<<<gEmb, 256, 0, stream>>>(rp0, pk0, embeds, embA);

  // stage 1: emb cur=embA -> next=embB, num cur=order0 -> num1, sums init
  k_emb_step<<<gEmb, 256, 0, stream>>>(rp1, pk1, order0, embA, embB, embS,
                                       order0, num1, numS, 1);
  // stage 2: emb cur=embB -> next=embA, num cur=num1 -> num2, sums +=
  k_emb_step<<<gEmb, 256, 0, stream>>>(rp2, pk2, order1, embB, embA, embS,
                                       num1, num2, numS, 2);
  // stage 3: sums += only
  k_emb_step<<<gEmb, 256, 0, stream>>>(rp3, pk3, order2, embA, embB, embS,
                                       num2, num1, numS, 3);

  k_final<<<(NN + 255) / 256, 256, 0, stream>>>(embeds, embS, numS, 0u, 7u, out, hist);
  k_cutoff<<<1, 1024, 0, stream>>>(hist, cnt2 + 1);
  k_collect<<<(NN + 255) / 256, 256, 0, stream>>>(out, cnt2 + 1, buf, cnt2);
  k_sort<<<1, 1024, 0, stream>>>(buf, cnt2, out + NN);
}